// Round 1
// baseline (18731.912 us; speedup 1.0000x reference)
//
#include <hip/hip_runtime.h>
#include <math.h>

#define H 64
#define ED 16
#define CO 16
static constexpr float EPSV = 1e-5f;

__device__ __forceinline__ float sigm(float z) { return 1.0f / (1.0f + __expf(-z)); }

// ---------------- prep: transposed/combined weights, self-loop consts, zero stats ----------------
// ws float layout (const area):
//   0: WeT1[64*16]  1024: WeGT1[64*16]  2048: WeT2  3072: WeGT2
//   4096: ets1[64] 4160: vs1[64] 4224: dv1[64]
//   4288: ets2[64] 4352: vs2[64] 4416: dv2[64]
//   4480: stats[4][2][64]   4992: norm[4][2][64]   (8192: deg[N], then big buffers)
__global__ void k_prep(const float* __restrict__ We1, const float* __restrict__ be1, const float* __restrict__ Wg1,
                       const float* __restrict__ We2, const float* __restrict__ be2, const float* __restrict__ Wg2,
                       float* __restrict__ ws) {
    int j = threadIdx.x;  // 0..63
    for (int l = 0; l < 2; ++l) {
        const float* We = l ? We2 : We1;
        const float* be = l ? be2 : be1;
        const float* Wg = l ? Wg2 : Wg1;
        float* WeT  = ws + (l ? 2048 : 0);
        float* WeGT = ws + (l ? 3072 : 1024);
        float* ets  = ws + (l ? 4288 : 4096);
        float* vs   = ws + (l ? 4352 : 4160);
        float* dv   = ws + (l ? 4416 : 4224);
        float et = be[j];
        for (int k = 0; k < ED; ++k) { float v = We[k * H + j]; WeT[j * ED + k] = v; et += v; }
        ets[j] = et;                                   // ea_t for self-loop (ea = ones)
        float d = 0.f;
        for (int m = 0; m < H; ++m) d += be[m] * Wg[(H + m) * H + j];
        dv[j] = d;                                     // be @ Wg_bot
        float vsum = d;
        for (int k = 0; k < ED; ++k) {
            float acc = 0.f;
            for (int m = 0; m < H; ++m) acc += We[k * H + m] * Wg[(H + m) * H + j];
            WeGT[j * ED + k] = acc;                    // (We @ Wg_bot)^T
            vsum += acc;
        }
        vs[j] = vsum;                                  // v for self-loop
    }
    for (int s = 0; s < 8; ++s) ws[4480 + s * 64 + j] = 0.f;  // zero all stats
}

// ---------------- init: agg = xin (self-loop), deg = 1 ----------------
template <int CIN>
__global__ void k_init(const float* __restrict__ xin, float* __restrict__ agg,
                       float* __restrict__ deg, int N) {
    int tid = blockIdx.x * blockDim.x + threadIdx.x;
    int n = tid / CIN, c = tid % CIN;
    if (n >= N) return;
    agg[(size_t)n * H + c] = xin[(size_t)n * CIN + c];
    if (deg != nullptr && c == 0) deg[n] = 1.0f;
}

// ---------------- edge pass 1: agg[col] += xin[row]; deg[col] += 1 ----------------
template <int CIN, bool DODEG>
__global__ void k_edge_agg(const int* __restrict__ rows, const int* __restrict__ cols,
                           const float* __restrict__ xin, float* __restrict__ agg,
                           float* __restrict__ deg, int E) {
    int e = blockIdx.x * blockDim.x + threadIdx.x;
    if (e >= E) return;
    int r = rows[e], c = cols[e];
    const float4* xr = reinterpret_cast<const float4*>(xin + (size_t)r * CIN);
    float* ar = agg + (size_t)c * H;
#pragma unroll
    for (int k4 = 0; k4 < CIN / 4; ++k4) {
        float4 v = xr[k4];
        atomicAdd(&ar[k4 * 4 + 0], v.x);
        atomicAdd(&ar[k4 * 4 + 1], v.y);
        atomicAdd(&ar[k4 * 4 + 2], v.z);
        atomicAdd(&ar[k4 * 4 + 3], v.w);
    }
    if (DODEG) atomicAdd(&deg[c], 1.0f);
}

// ---------------- node matmuls: pre = (agg/deg)@Wl + bl + x@Wr ; u = pre@Wg_top + bg ;
//                  contrib = sigmoid(u + v_self) * et_self  (self-loop folded) ----------------
template <int CIN>
__global__ void k_node_mm(const float* __restrict__ xin, const float* __restrict__ agg,
                          const float* __restrict__ deg,
                          const float* __restrict__ Wl, const float* __restrict__ bl,
                          const float* __restrict__ Wr,
                          const float* __restrict__ Wg, const float* __restrict__ bg,
                          const float* __restrict__ ets, const float* __restrict__ vs,
                          float* __restrict__ pre, float* __restrict__ u,
                          float* __restrict__ contrib, int N) {
    int n = blockIdx.x * blockDim.x + threadIdx.x;
    if (n >= N) return;
    float out[H];
#pragma unroll
    for (int j = 0; j < H; ++j) out[j] = bl[j];
    float invdeg = 1.0f / fmaxf(deg[n], 1.0f);
    const float* ar = agg + (size_t)n * H;
    const float* xr = xin + (size_t)n * CIN;
    for (int k = 0; k < CIN; ++k) {
        float ak = ar[k] * invdeg;
        float xk = xr[k];
        const float* wl = Wl + k * H;
        const float* wr = Wr + k * H;
#pragma unroll
        for (int j = 0; j < H; ++j) out[j] += ak * wl[j] + xk * wr[j];
    }
    float* prow = pre + (size_t)n * H;
#pragma unroll
    for (int j4 = 0; j4 < H / 4; ++j4)
        reinterpret_cast<float4*>(prow)[j4] = make_float4(out[j4*4+0], out[j4*4+1], out[j4*4+2], out[j4*4+3]);
    // u = out @ Wg_top + bg  (re-read own row to avoid dynamic register indexing)
    float ua[H];
#pragma unroll
    for (int j = 0; j < H; ++j) ua[j] = bg[j];
    for (int m = 0; m < H; ++m) {
        float om = prow[m];
        const float* wg = Wg + m * H;
#pragma unroll
        for (int j = 0; j < H; ++j) ua[j] += om * wg[j];
    }
    float* urow = u + (size_t)n * H;
    float* crow = contrib + (size_t)n * H;
#pragma unroll
    for (int j4 = 0; j4 < H / 4; ++j4) {
        float4 uv = make_float4(ua[j4*4+0], ua[j4*4+1], ua[j4*4+2], ua[j4*4+3]);
        reinterpret_cast<float4*>(urow)[j4] = uv;
        float4 cv;
        cv.x = sigm(uv.x + vs[j4*4+0]) * ets[j4*4+0];
        cv.y = sigm(uv.y + vs[j4*4+1]) * ets[j4*4+1];
        cv.z = sigm(uv.z + vs[j4*4+2]) * ets[j4*4+2];
        cv.w = sigm(uv.w + vs[j4*4+3]) * ets[j4*4+3];
        reinterpret_cast<float4*>(crow)[j4] = cv;
    }
}

// ---------------- edge pass 2: contrib[col] += sigmoid(u[col] + ea@WeG + d) * (ea@We + be) ----------------
__global__ void k_edge_gate(const int* __restrict__ cols, const float* __restrict__ ea,
                            const float* __restrict__ WeT, const float* __restrict__ WeGT,
                            const float* __restrict__ be, const float* __restrict__ dv,
                            const float* __restrict__ u, float* __restrict__ contrib, int E) {
    int e = blockIdx.x * blockDim.x + threadIdx.x;
    if (e >= E) return;
    int c = cols[e];
    float eav[ED];
    const float4* er = reinterpret_cast<const float4*>(ea + (size_t)e * ED);
#pragma unroll
    for (int k4 = 0; k4 < ED / 4; ++k4) {
        float4 v = er[k4];
        eav[k4*4+0] = v.x; eav[k4*4+1] = v.y; eav[k4*4+2] = v.z; eav[k4*4+3] = v.w;
    }
    const float* urow = u + (size_t)c * H;
    float* crow = contrib + (size_t)c * H;
#pragma unroll 4
    for (int j = 0; j < H; ++j) {
        float et = be[j], v = dv[j];
#pragma unroll
        for (int k = 0; k < ED; ++k) {
            et += eav[k] * WeT[j * ED + k];
            v  += eav[k] * WeGT[j * ED + k];
        }
        float g = sigm(urow[j] + v);
        atomicAdd(&crow[j], g * et);
    }
}

// ---------------- t = pre + contrib (in place into pre) + batch stats ----------------
__global__ void k_addstats(float* __restrict__ pre, const float* __restrict__ contrib,
                           float* __restrict__ s1, float* __restrict__ s2, int N) {
    int j = threadIdx.x, ty = threadIdx.y;
    float s = 0.f, ss = 0.f;
    for (int n = blockIdx.x * 4 + ty; n < N; n += gridDim.x * 4) {
        size_t idx = (size_t)n * H + j;
        float val = pre[idx] + contrib[idx];
        pre[idx] = val;
        s += val; ss += val * val;
    }
    __shared__ float ls[2][4][H];
    ls[0][ty][j] = s; ls[1][ty][j] = ss;
    __syncthreads();
    if (ty == 0) {
        float a = ls[0][0][j] + ls[0][1][j] + ls[0][2][j] + ls[0][3][j];
        float b = ls[1][0][j] + ls[1][1][j] + ls[1][2][j] + ls[1][3][j];
        atomicAdd(&s1[j], a);
        atomicAdd(&s2[j], b);
    }
}

// ---------------- finalize stats -> mu_s = a*mean, rsig ----------------
__global__ void k_finalize(const float* __restrict__ s1, const float* __restrict__ s2,
                           const float* __restrict__ avec, float* __restrict__ mu_s,
                           float* __restrict__ rsig, float Ninv) {
    int j = threadIdx.x;
    float m1 = s1[j] * Ninv, m2 = s2[j] * Ninv;
    float a = avec ? avec[j] : 1.0f;
    float var = m2 - 2.f * a * m1 * m1 + a * a * m1 * m1;
    mu_s[j] = a * m1;
    rsig[j] = rsqrtf(var + EPSV);
}

// ---------------- out = relu(scale*(gamma*(in-mu_s)*rsig + beta)) (+ optional stats) ----------------
template <bool STATS>
__global__ void k_apply(const float* __restrict__ in, float* __restrict__ outb,
                        const float* __restrict__ mu_s, const float* __restrict__ rsig,
                        const float* __restrict__ gamma, const float* __restrict__ beta,
                        float scale, float* __restrict__ s1, float* __restrict__ s2, int N) {
    int j = threadIdx.x, ty = threadIdx.y;
    float mm = mu_s[j], rs = rsig[j], gm = gamma[j], bt = beta[j];
    float s = 0.f, ss = 0.f;
    for (int n = blockIdx.x * 4 + ty; n < N; n += gridDim.x * 4) {
        size_t idx = (size_t)n * H + j;
        float v = (in[idx] - mm) * rs * gm + bt;
        v = fmaxf(scale * v, 0.f);
        outb[idx] = v;
        if (STATS) { s += v; ss += v * v; }
    }
    if (STATS) {
        __shared__ float ls[2][4][H];
        ls[0][ty][j] = s; ls[1][ty][j] = ss;
        __syncthreads();
        if (ty == 0) {
            float a = ls[0][0][j] + ls[0][1][j] + ls[0][2][j] + ls[0][3][j];
            float b = ls[1][0][j] + ls[1][1][j] + ls[1][2][j] + ls[1][3][j];
            atomicAdd(&s1[j], a);
            atomicAdd(&s2[j], b);
        }
    }
}

// ---------------- final linear: d_out = hg @ lin_W + lin_b ----------------
__global__ void k_final(const float* __restrict__ hg, const float* __restrict__ W,
                        const float* __restrict__ b, float* __restrict__ outp, int N) {
    int n = blockIdx.x * blockDim.x + threadIdx.x;
    if (n >= N) return;
    float o[CO];
#pragma unroll
    for (int t = 0; t < CO; ++t) o[t] = b[t];
    const float4* hr = reinterpret_cast<const float4*>(hg + (size_t)n * H);
    for (int m4 = 0; m4 < H / 4; ++m4) {
        float4 h4 = hr[m4];
#pragma unroll
        for (int t = 0; t < CO; ++t) {
            o[t] += h4.x * W[(m4*4+0) * CO + t];
            o[t] += h4.y * W[(m4*4+1) * CO + t];
            o[t] += h4.z * W[(m4*4+2) * CO + t];
            o[t] += h4.w * W[(m4*4+3) * CO + t];
        }
    }
    float* orow = outp + (size_t)n * CO;
#pragma unroll
    for (int t4 = 0; t4 < CO / 4; ++t4)
        reinterpret_cast<float4*>(orow)[t4] = make_float4(o[t4*4+0], o[t4*4+1], o[t4*4+2], o[t4*4+3]);
}

extern "C" void kernel_launch(void* const* d_in, const int* in_sizes, int n_in,
                              void* d_out, int out_size, void* d_ws, size_t ws_size,
                              hipStream_t stream) {
    const float* x     = (const float*)d_in[0];
    const int*   ei    = (const int*)d_in[1];
    const float* ea    = (const float*)d_in[2];
    const float* l1_Wl = (const float*)d_in[3];  const float* l1_bl = (const float*)d_in[4];
    const float* l1_Wr = (const float*)d_in[5];  const float* l1_We = (const float*)d_in[6];
    const float* l1_be = (const float*)d_in[7];  const float* l1_Wg = (const float*)d_in[8];
    const float* l1_bg = (const float*)d_in[9];  const float* l1_bng= (const float*)d_in[10];
    const float* l1_bnb= (const float*)d_in[11];
    const float* l2_Wl = (const float*)d_in[12]; const float* l2_bl = (const float*)d_in[13];
    const float* l2_Wr = (const float*)d_in[14]; const float* l2_We = (const float*)d_in[15];
    const float* l2_be = (const float*)d_in[16]; const float* l2_Wg = (const float*)d_in[17];
    const float* l2_bg = (const float*)d_in[18]; const float* l2_bng= (const float*)d_in[19];
    const float* l2_bnb= (const float*)d_in[20];
    const float* gn1_g = (const float*)d_in[21]; const float* gn1_b = (const float*)d_in[22];
    const float* gn1_a = (const float*)d_in[23];
    const float* gn2_g = (const float*)d_in[24]; const float* gn2_b = (const float*)d_in[25];
    const float* gn2_a = (const float*)d_in[26];
    const float* lin_W = (const float*)d_in[27]; const float* lin_b = (const float*)d_in[28];

    const int N = in_sizes[0] / 32;
    const int E = in_sizes[1] / 2;
    const int* rows = ei;
    const int* cols = ei + E;

    float* w     = (float*)d_ws;
    float* WeT1  = w;         float* WeGT1 = w + 1024;
    float* WeT2  = w + 2048;  float* WeGT2 = w + 3072;
    float* ets1  = w + 4096;  float* vs1   = w + 4160;  float* dv1 = w + 4224;
    float* ets2  = w + 4288;  float* vs2   = w + 4352;  float* dv2 = w + 4416;
    float* stats = w + 4480;  // 4 sets of (s1[64], s2[64])
    float* norm  = w + 4992;  // 4 sets of (mu_s[64], rsig[64])
    float* deg   = w + 8192;
    size_t NB = (size_t)N * H;
    float* Bagg = deg + (((size_t)N + 127) & ~(size_t)127);
    float* Bpre = Bagg + NB;
    float* Bu   = Bpre + NB;
    float* Bct  = Bu + NB;
    float* Bhg  = Bct + NB;

    const float Ninv = 1.0f / (float)N;
    dim3 rb(64, 4);
    int egrid = (E + 255) / 256;
    int ngrid = (N + 255) / 256;

    k_prep<<<1, 64, 0, stream>>>(l1_We, l1_be, l1_Wg, l2_We, l2_be, l2_Wg, w);

    // ---- layer 1 (CIN=32) ----
    k_init<32><<<(N * 32 + 255) / 256, 256, 0, stream>>>(x, Bagg, deg, N);
    k_edge_agg<32, true><<<egrid, 256, 0, stream>>>(rows, cols, x, Bagg, deg, E);
    k_node_mm<32><<<ngrid, 256, 0, stream>>>(x, Bagg, deg, l1_Wl, l1_bl, l1_Wr, l1_Wg, l1_bg,
                                             ets1, vs1, Bpre, Bu, Bct, N);
    k_edge_gate<<<egrid, 256, 0, stream>>>(cols, ea, WeT1, WeGT1, l1_be, dv1, Bu, Bct, E);
    k_addstats<<<256, rb, 0, stream>>>(Bpre, Bct, stats + 0, stats + 64, N);
    k_finalize<<<1, 64, 0, stream>>>(stats + 0, stats + 64, nullptr, norm + 0, norm + 64, Ninv);
    k_apply<true><<<256, rb, 0, stream>>>(Bpre, Bagg, norm + 0, norm + 64, l1_bng, l1_bnb, 2.0f,
                                          stats + 128, stats + 192, N);
    k_finalize<<<1, 64, 0, stream>>>(stats + 128, stats + 192, gn1_a, norm + 128, norm + 192, Ninv);
    k_apply<false><<<256, rb, 0, stream>>>(Bagg, Bhg, norm + 128, norm + 192, gn1_g, gn1_b, 1.0f,
                                           nullptr, nullptr, N);

    // ---- layer 2 (CIN=64) ----
    k_init<64><<<(N * 64 + 255) / 256, 256, 0, stream>>>(Bhg, Bagg, nullptr, N);
    k_edge_agg<64, false><<<egrid, 256, 0, stream>>>(rows, cols, Bhg, Bagg, nullptr, E);
    k_node_mm<64><<<ngrid, 256, 0, stream>>>(Bhg, Bagg, deg, l2_Wl, l2_bl, l2_Wr, l2_Wg, l2_bg,
                                             ets2, vs2, Bpre, Bu, Bct, N);
    k_edge_gate<<<egrid, 256, 0, stream>>>(cols, ea, WeT2, WeGT2, l2_be, dv2, Bu, Bct, E);
    k_addstats<<<256, rb, 0, stream>>>(Bpre, Bct, stats + 256, stats + 320, N);
    k_finalize<<<1, 64, 0, stream>>>(stats + 256, stats + 320, nullptr, norm + 256, norm + 320, Ninv);
    k_apply<true><<<256, rb, 0, stream>>>(Bpre, Bagg, norm + 256, norm + 320, l2_bng, l2_bnb, 2.0f,
                                          stats + 384, stats + 448, N);
    k_finalize<<<1, 64, 0, stream>>>(stats + 384, stats + 448, gn2_a, norm + 384, norm + 448, Ninv);
    k_apply<false><<<256, rb, 0, stream>>>(Bagg, Bhg, norm + 384, norm + 448, gn2_g, gn2_b, 1.0f,
                                           nullptr, nullptr, N);

    k_final<<<ngrid, 256, 0, stream>>>(Bhg, lin_W, lin_b, (float*)d_out, N);
}

// Round 2
// 1815.230 us; speedup vs baseline: 10.3193x; 10.3193x over previous
//
#include <hip/hip_runtime.h>
#include <math.h>

#define H 64
#define ED 16
#define CO 16
static constexpr float EPSV = 1e-5f;

__device__ __forceinline__ float sigm(float z) { return 1.0f / (1.0f + __expf(-z)); }

// ---------------- prep: transposed/combined weights, self-loop consts, zero stats ----------------
// ws float layout (const area, 8192 floats):
//   0: WeT1[64*16]  1024: WeGT1[64*16]  2048: WeT2  3072: WeGT2
//   4096: ets1[64] 4160: vs1[64] 4224: dv1[64]
//   4288: ets2[64] 4352: vs2[64] 4416: dv2[64]
//   4480: stats[4][2][64]   4992: norm[4][2][64]
__global__ void k_prep(const float* __restrict__ We1, const float* __restrict__ be1, const float* __restrict__ Wg1,
                       const float* __restrict__ We2, const float* __restrict__ be2, const float* __restrict__ Wg2,
                       float* __restrict__ ws) {
    int j = threadIdx.x;  // 0..63
    for (int l = 0; l < 2; ++l) {
        const float* We = l ? We2 : We1;
        const float* be = l ? be2 : be1;
        const float* Wg = l ? Wg2 : Wg1;
        float* WeT  = ws + (l ? 2048 : 0);
        float* WeGT = ws + (l ? 3072 : 1024);
        float* ets  = ws + (l ? 4288 : 4096);
        float* vs   = ws + (l ? 4352 : 4160);
        float* dv   = ws + (l ? 4416 : 4224);
        float et = be[j];
        for (int k = 0; k < ED; ++k) { float v = We[k * H + j]; WeT[j * ED + k] = v; et += v; }
        ets[j] = et;                                   // ea_t for self-loop (ea = ones)
        float d = 0.f;
        for (int m = 0; m < H; ++m) d += be[m] * Wg[(H + m) * H + j];
        dv[j] = d;                                     // be @ Wg_bot
        float vsum = d;
        for (int k = 0; k < ED; ++k) {
            float acc = 0.f;
            for (int m = 0; m < H; ++m) acc += We[k * H + m] * Wg[(H + m) * H + j];
            WeGT[j * ED + k] = acc;                    // (We @ Wg_bot)^T
            vsum += acc;
        }
        vs[j] = vsum;                                  // v for self-loop
    }
    for (int s = 0; s < 8; ++s) ws[4480 + s * 64 + j] = 0.f;  // zero all stats (re-zeroed every launch)
}

// ---------------- CSR build ----------------
__global__ void k_zero2(int* __restrict__ cnt, int* __restrict__ cur, int N) {
    int i = blockIdx.x * blockDim.x + threadIdx.x;
    if (i < N) { cnt[i] = 0; cur[i] = 0; }
}

__global__ void k_count(const int* __restrict__ cols, int* __restrict__ cnt, int E) {
    int e = blockIdx.x * blockDim.x + threadIdx.x;
    if (e < E) atomicAdd(&cnt[cols[e]], 1);
}

__global__ __launch_bounds__(1024) void k_scan(const int* __restrict__ cnt, int* __restrict__ rowptr, int N) {
    const int T = 1024;
    int t = threadIdx.x;
    int C = (N + T - 1) / T;
    int b = t * C, e = min(b + C, N);
    int sum = 0;
    for (int i = b; i < e; ++i) sum += cnt[i];
    __shared__ int ls[T];
    ls[t] = sum;
    __syncthreads();
    for (int off = 1; off < T; off <<= 1) {
        int v = (t >= off) ? ls[t - off] : 0;
        __syncthreads();
        ls[t] += v;
        __syncthreads();
    }
    int running = ls[t] - sum;  // exclusive base
    for (int i = b; i < e; ++i) {
        int c = cnt[i];
        rowptr[i] = running;
        running += c;
    }
    if (b < N && e == N) rowptr[N] = running;
}

__global__ void k_scatter(const int* __restrict__ rows, const int* __restrict__ cols,
                          const int* __restrict__ rowptr, int* __restrict__ cur,
                          int* __restrict__ erow, int* __restrict__ eid, int E) {
    int e = blockIdx.x * blockDim.x + threadIdx.x;
    if (e >= E) return;
    int c = cols[e];
    int p = rowptr[c] + atomicAdd(&cur[c], 1);
    erow[p] = rows[e];
    eid[p] = e;
}

// ---------------- gather: agg[n] = x[n] + sum_{in-edges} x[row]  (wave per node, no atomics) ----------------
template <int CIN>
__global__ void k_gather(const float* __restrict__ x, const int* __restrict__ rowptr,
                         const int* __restrict__ erow, float* __restrict__ agg, int N) {
    int lane = threadIdx.x & 63;
    int wid = (blockIdx.x * blockDim.x + threadIdx.x) >> 6;
    int nw = (gridDim.x * blockDim.x) >> 6;
    for (int n = wid; n < N; n += nw) {
        int s = rowptr[n], t = rowptr[n + 1];
        if (CIN == 64) {
            float acc = x[(size_t)n * 64 + lane];
            for (int i = s; i < t; ++i) {
                int r = erow[i];
                acc += x[(size_t)r * 64 + lane];
            }
            agg[(size_t)n * H + lane] = acc;
        } else {
            int c = lane & 31, half = lane >> 5;
            float acc = half ? 0.f : x[(size_t)n * 32 + c];
            for (int i = s + half; i < t; i += 2) {
                int r = erow[i];
                acc += x[(size_t)r * 32 + c];
            }
            acc += __shfl_xor(acc, 32);
            if (half == 0) agg[(size_t)n * H + c] = acc;
        }
    }
}

// ---------------- node matmuls: pre = (agg/deg)@Wl + bl + x@Wr ; u = pre@Wg_top + bg ----------------
template <int CIN>
__global__ void k_node_mm(const float* __restrict__ xin, const float* __restrict__ agg,
                          const int* __restrict__ rowptr,
                          const float* __restrict__ Wl, const float* __restrict__ bl,
                          const float* __restrict__ Wr,
                          const float* __restrict__ Wg, const float* __restrict__ bg,
                          float* __restrict__ pre, float* __restrict__ u, int N) {
    int n = blockIdx.x * blockDim.x + threadIdx.x;
    if (n >= N) return;
    float out[H];
#pragma unroll
    for (int j = 0; j < H; ++j) out[j] = bl[j];
    float invdeg = 1.0f / (float)(rowptr[n + 1] - rowptr[n] + 1);
    const float* ar = agg + (size_t)n * H;
    const float* xr = xin + (size_t)n * CIN;
    for (int k = 0; k < CIN; ++k) {
        float ak = ar[k] * invdeg;
        float xk = xr[k];
        const float* wl = Wl + k * H;
        const float* wr = Wr + k * H;
#pragma unroll
        for (int j = 0; j < H; ++j) out[j] += ak * wl[j] + xk * wr[j];
    }
    float* prow = pre + (size_t)n * H;
#pragma unroll
    for (int j4 = 0; j4 < H / 4; ++j4)
        reinterpret_cast<float4*>(prow)[j4] = make_float4(out[j4*4+0], out[j4*4+1], out[j4*4+2], out[j4*4+3]);
    // u = out @ Wg_top + bg  (re-read own row to avoid dynamic register indexing)
    float ua[H];
#pragma unroll
    for (int j = 0; j < H; ++j) ua[j] = bg[j];
    for (int m = 0; m < H; ++m) {
        float om = prow[m];
        const float* wg = Wg + m * H;
#pragma unroll
        for (int j = 0; j < H; ++j) ua[j] += om * wg[j];
    }
    float* urow = u + (size_t)n * H;
#pragma unroll
    for (int j4 = 0; j4 < H / 4; ++j4)
        reinterpret_cast<float4*>(urow)[j4] = make_float4(ua[j4*4+0], ua[j4*4+1], ua[j4*4+2], ua[j4*4+3]);
}

// ---------------- gate + self-contrib + add + batch stats (wave per node, no atomics on rows) ----------------
__global__ __launch_bounds__(256) void k_gate(const int* __restrict__ rowptr, const int* __restrict__ eid,
                      const float* __restrict__ ea,
                      const float* __restrict__ WeT, const float* __restrict__ WeGT,
                      const float* __restrict__ be, const float* __restrict__ dv,
                      const float* __restrict__ ets, const float* __restrict__ vs,
                      const float* __restrict__ u, float* __restrict__ pre,
                      float* __restrict__ s1, float* __restrict__ s2, int N) {
    int lane = threadIdx.x & 63;
    int wv = threadIdx.x >> 6;  // 0..3
    int wid = (blockIdx.x * blockDim.x + threadIdx.x) >> 6;
    int nw = (gridDim.x * blockDim.x) >> 6;
    float wt[ED], wg[ED];
#pragma unroll
    for (int k = 0; k < ED; ++k) { wt[k] = WeT[lane * ED + k]; wg[k] = WeGT[lane * ED + k]; }
    float be_l = be[lane], dv_l = dv[lane], ets_l = ets[lane], vs_l = vs[lane];
    float s = 0.f, ss = 0.f;
    for (int n = wid; n < N; n += nw) {
        float u_l = u[(size_t)n * H + lane];
        float acc = sigm(u_l + vs_l) * ets_l;  // folded self-loop contribution
        int s0 = rowptr[n], t0 = rowptr[n + 1];
        for (int i = s0; i < t0; ++i) {
            int e = eid[i];
            const float4* er = reinterpret_cast<const float4*>(ea + (size_t)e * ED);
            float4 a0 = er[0], a1 = er[1], a2 = er[2], a3 = er[3];
            float eav[ED] = {a0.x, a0.y, a0.z, a0.w, a1.x, a1.y, a1.z, a1.w,
                             a2.x, a2.y, a2.z, a2.w, a3.x, a3.y, a3.z, a3.w};
            float et = be_l, v = dv_l;
#pragma unroll
            for (int k = 0; k < ED; ++k) { et += eav[k] * wt[k]; v += eav[k] * wg[k]; }
            acc += sigm(u_l + v) * et;
        }
        size_t idx = (size_t)n * H + lane;
        float tval = pre[idx] + acc;
        pre[idx] = tval;
        s += tval; ss += tval * tval;
    }
    __shared__ float ls[2][4][H];
    ls[0][wv][lane] = s; ls[1][wv][lane] = ss;
    __syncthreads();
    if (threadIdx.x < H) {
        float a = ls[0][0][lane] + ls[0][1][lane] + ls[0][2][lane] + ls[0][3][lane];
        float b = ls[1][0][lane] + ls[1][1][lane] + ls[1][2][lane] + ls[1][3][lane];
        atomicAdd(&s1[lane], a);
        atomicAdd(&s2[lane], b);
    }
}

// ---------------- finalize stats -> mu_s = a*mean, rsig ----------------
__global__ void k_finalize(const float* __restrict__ s1, const float* __restrict__ s2,
                           const float* __restrict__ avec, float* __restrict__ mu_s,
                           float* __restrict__ rsig, float Ninv) {
    int j = threadIdx.x;
    float m1 = s1[j] * Ninv, m2 = s2[j] * Ninv;
    float a = avec ? avec[j] : 1.0f;
    float var = m2 - 2.f * a * m1 * m1 + a * a * m1 * m1;
    mu_s[j] = a * m1;
    rsig[j] = rsqrtf(var + EPSV);
}

// ---------------- out = relu(scale*(gamma*(in-mu_s)*rsig + beta)) (+ optional stats) ----------------
template <bool STATS>
__global__ void k_apply(const float* __restrict__ in, float* __restrict__ outb,
                        const float* __restrict__ mu_s, const float* __restrict__ rsig,
                        const float* __restrict__ gamma, const float* __restrict__ beta,
                        float scale, float* __restrict__ s1, float* __restrict__ s2, int N) {
    int j = threadIdx.x, ty = threadIdx.y;
    float mm = mu_s[j], rs = rsig[j], gm = gamma[j], bt = beta[j];
    float s = 0.f, ss = 0.f;
    for (int n = blockIdx.x * 4 + ty; n < N; n += gridDim.x * 4) {
        size_t idx = (size_t)n * H + j;
        float v = (in[idx] - mm) * rs * gm + bt;
        v = fmaxf(scale * v, 0.f);
        outb[idx] = v;
        if (STATS) { s += v; ss += v * v; }
    }
    if (STATS) {
        __shared__ float ls[2][4][H];
        ls[0][ty][j] = s; ls[1][ty][j] = ss;
        __syncthreads();
        if (ty == 0) {
            float a = ls[0][0][j] + ls[0][1][j] + ls[0][2][j] + ls[0][3][j];
            float b = ls[1][0][j] + ls[1][1][j] + ls[1][2][j] + ls[1][3][j];
            atomicAdd(&s1[j], a);
            atomicAdd(&s2[j], b);
        }
    }
}

// ---------------- final linear: d_out = hg @ lin_W + lin_b ----------------
__global__ void k_final(const float* __restrict__ hg, const float* __restrict__ W,
                        const float* __restrict__ b, float* __restrict__ outp, int N) {
    int n = blockIdx.x * blockDim.x + threadIdx.x;
    if (n >= N) return;
    float o[CO];
#pragma unroll
    for (int t = 0; t < CO; ++t) o[t] = b[t];
    const float4* hr = reinterpret_cast<const float4*>(hg + (size_t)n * H);
    for (int m4 = 0; m4 < H / 4; ++m4) {
        float4 h4 = hr[m4];
#pragma unroll
        for (int t = 0; t < CO; ++t) {
            o[t] += h4.x * W[(m4*4+0) * CO + t];
            o[t] += h4.y * W[(m4*4+1) * CO + t];
            o[t] += h4.z * W[(m4*4+2) * CO + t];
            o[t] += h4.w * W[(m4*4+3) * CO + t];
        }
    }
    float* orow = outp + (size_t)n * CO;
#pragma unroll
    for (int t4 = 0; t4 < CO / 4; ++t4)
        reinterpret_cast<float4*>(orow)[t4] = make_float4(o[t4*4+0], o[t4*4+1], o[t4*4+2], o[t4*4+3]);
}

extern "C" void kernel_launch(void* const* d_in, const int* in_sizes, int n_in,
                              void* d_out, int out_size, void* d_ws, size_t ws_size,
                              hipStream_t stream) {
    const float* x     = (const float*)d_in[0];
    const int*   ei    = (const int*)d_in[1];
    const float* ea    = (const float*)d_in[2];
    const float* l1_Wl = (const float*)d_in[3];  const float* l1_bl = (const float*)d_in[4];
    const float* l1_Wr = (const float*)d_in[5];  const float* l1_We = (const float*)d_in[6];
    const float* l1_be = (const float*)d_in[7];  const float* l1_Wg = (const float*)d_in[8];
    const float* l1_bg = (const float*)d_in[9];  const float* l1_bng= (const float*)d_in[10];
    const float* l1_bnb= (const float*)d_in[11];
    const float* l2_Wl = (const float*)d_in[12]; const float* l2_bl = (const float*)d_in[13];
    const float* l2_Wr = (const float*)d_in[14]; const float* l2_We = (const float*)d_in[15];
    const float* l2_be = (const float*)d_in[16]; const float* l2_Wg = (const float*)d_in[17];
    const float* l2_bg = (const float*)d_in[18]; const float* l2_bng= (const float*)d_in[19];
    const float* l2_bnb= (const float*)d_in[20];
    const float* gn1_g = (const float*)d_in[21]; const float* gn1_b = (const float*)d_in[22];
    const float* gn1_a = (const float*)d_in[23];
    const float* gn2_g = (const float*)d_in[24]; const float* gn2_b = (const float*)d_in[25];
    const float* gn2_a = (const float*)d_in[26];
    const float* lin_W = (const float*)d_in[27]; const float* lin_b = (const float*)d_in[28];

    const int N = in_sizes[0] / 32;
    const int E = in_sizes[1] / 2;
    const int* rows = ei;
    const int* cols = ei + E;

    float* w     = (float*)d_ws;
    float* WeT1  = w;         float* WeGT1 = w + 1024;
    float* WeT2  = w + 2048;  float* WeGT2 = w + 3072;
    float* ets1  = w + 4096;  float* vs1   = w + 4160;  float* dv1 = w + 4224;
    float* ets2  = w + 4288;  float* vs2   = w + 4352;  float* dv2 = w + 4416;
    float* stats = w + 4480;  // 4 sets of (s1[64], s2[64])
    float* norm  = w + 4992;  // 4 sets of (mu_s[64], rsig[64])

    int* ip     = (int*)(w + 8192);
    int* rowptr = ip;                 // N+1
    int* cnt    = ip + (N + 1);       // N
    int* cur    = cnt + N;            // N
    int* erow   = cur + N;            // E
    int* eid    = erow + E;           // E
    size_t intcnt = ((size_t)(3 * (size_t)N + 1 + 2 * (size_t)E) + 3) & ~(size_t)3;
    float* Bagg = (float*)(ip + intcnt);
    size_t NB = (size_t)N * H;
    float* Bpre = Bagg + NB;
    float* Bu   = Bpre + NB;
    float* Bhg  = Bu + NB;

    const float Ninv = 1.0f / (float)N;
    dim3 rb(64, 4);
    int egrid = (E + 255) / 256;
    int ngrid = (N + 255) / 256;
    int wgrid = 1024;  // wave-per-node grid-stride kernels: 4096 waves

    k_prep<<<1, 64, 0, stream>>>(l1_We, l1_be, l1_Wg, l2_We, l2_be, l2_Wg, w);

    // ---- CSR build (by destination col) ----
    k_zero2<<<(N + 255) / 256, 256, 0, stream>>>(cnt, cur, N);
    k_count<<<egrid, 256, 0, stream>>>(cols, cnt, E);
    k_scan<<<1, 1024, 0, stream>>>(cnt, rowptr, N);
    k_scatter<<<egrid, 256, 0, stream>>>(rows, cols, rowptr, cur, erow, eid, E);

    // ---- layer 1 (CIN=32) ----
    k_gather<32><<<wgrid, 256, 0, stream>>>(x, rowptr, erow, Bagg, N);
    k_node_mm<32><<<ngrid, 256, 0, stream>>>(x, Bagg, rowptr, l1_Wl, l1_bl, l1_Wr, l1_Wg, l1_bg,
                                             Bpre, Bu, N);
    k_gate<<<wgrid, 256, 0, stream>>>(rowptr, eid, ea, WeT1, WeGT1, l1_be, dv1, ets1, vs1,
                                      Bu, Bpre, stats + 0, stats + 64, N);
    k_finalize<<<1, 64, 0, stream>>>(stats + 0, stats + 64, nullptr, norm + 0, norm + 64, Ninv);
    k_apply<true><<<256, rb, 0, stream>>>(Bpre, Bagg, norm + 0, norm + 64, l1_bng, l1_bnb, 2.0f,
                                          stats + 128, stats + 192, N);
    k_finalize<<<1, 64, 0, stream>>>(stats + 128, stats + 192, gn1_a, norm + 128, norm + 192, Ninv);
    k_apply<false><<<256, rb, 0, stream>>>(Bagg, Bhg, norm + 128, norm + 192, gn1_g, gn1_b, 1.0f,
                                           nullptr, nullptr, N);

    // ---- layer 2 (CIN=64) ----
    k_gather<64><<<wgrid, 256, 0, stream>>>(Bhg, rowptr, erow, Bagg, N);
    k_node_mm<64><<<ngrid, 256, 0, stream>>>(Bhg, Bagg, rowptr, l2_Wl, l2_bl, l2_Wr, l2_Wg, l2_bg,
                                             Bpre, Bu, N);
    k_gate<<<wgrid, 256, 0, stream>>>(rowptr, eid, ea, WeT2, WeGT2, l2_be, dv2, ets2, vs2,
                                      Bu, Bpre, stats + 256, stats + 320, N);
    k_finalize<<<1, 64, 0, stream>>>(stats + 256, stats + 320, nullptr, norm + 256, norm + 320, Ninv);
    k_apply<true><<<256, rb, 0, stream>>>(Bpre, Bagg, norm + 256, norm + 320, l2_bng, l2_bnb, 2.0f,
                                          stats + 384, stats + 448, N);
    k_finalize<<<1, 64, 0, stream>>>(stats + 384, stats + 448, gn2_a, norm + 384, norm + 448, Ninv);
    k_apply<false><<<256, rb, 0, stream>>>(Bagg, Bhg, norm + 384, norm + 448, gn2_g, gn2_b, 1.0f,
                                           nullptr, nullptr, N);

    k_final<<<ngrid, 256, 0, stream>>>(Bhg, lin_W, lin_b, (float*)d_out, N);
}

// Round 3
// 1457.508 us; speedup vs baseline: 12.8520x; 1.2454x over previous
//
#include <hip/hip_runtime.h>
#include <math.h>

#define H 64
#define ED 16
#define CO 16
static constexpr float EPSV = 1e-5f;

__device__ __forceinline__ float sigm(float z) { return 1.0f / (1.0f + __expf(-z)); }

// ---------------- prep: transposed/combined weights, self-loop consts, zero stats ----------------
// ws float layout (const area, 8192 floats):
//   0: WeT1[64*16]  1024: WeGT1[64*16]  2048: WeT2  3072: WeGT2
//   4096: ets1[64] 4160: vs1[64] 4224: dv1[64]
//   4288: ets2[64] 4352: vs2[64] 4416: dv2[64]
//   4480: stats[4][2][64]   4992: norm[4][2][64]
__global__ void k_prep(const float* __restrict__ We1, const float* __restrict__ be1, const float* __restrict__ Wg1,
                       const float* __restrict__ We2, const float* __restrict__ be2, const float* __restrict__ Wg2,
                       float* __restrict__ ws) {
    int j = threadIdx.x;  // 0..63
    for (int l = 0; l < 2; ++l) {
        const float* We = l ? We2 : We1;
        const float* be = l ? be2 : be1;
        const float* Wg = l ? Wg2 : Wg1;
        float* WeT  = ws + (l ? 2048 : 0);
        float* WeGT = ws + (l ? 3072 : 1024);
        float* ets  = ws + (l ? 4288 : 4096);
        float* vs   = ws + (l ? 4352 : 4160);
        float* dv   = ws + (l ? 4416 : 4224);
        float et = be[j];
        for (int k = 0; k < ED; ++k) { float v = We[k * H + j]; WeT[j * ED + k] = v; et += v; }
        ets[j] = et;                                   // ea_t for self-loop (ea = ones)
        float d = 0.f;
        for (int m = 0; m < H; ++m) d += be[m] * Wg[(H + m) * H + j];
        dv[j] = d;                                     // be @ Wg_bot
        float vsum = d;
        for (int k = 0; k < ED; ++k) {
            float acc = 0.f;
            for (int m = 0; m < H; ++m) acc += We[k * H + m] * Wg[(H + m) * H + j];
            WeGT[j * ED + k] = acc;                    // (We @ Wg_bot)^T
            vsum += acc;
        }
        vs[j] = vsum;                                  // v for self-loop
    }
    for (int s = 0; s < 8; ++s) ws[4480 + s * 64 + j] = 0.f;  // zero all stats (re-zeroed every launch)
}

// ---------------- CSR build ----------------
__global__ void k_zero2(int* __restrict__ cnt, int* __restrict__ cur, int N) {
    int i = blockIdx.x * blockDim.x + threadIdx.x;
    if (i < N) { cnt[i] = 0; cur[i] = 0; }
}

__global__ void k_count(const int* __restrict__ cols, int* __restrict__ cnt, int E) {
    int e = blockIdx.x * blockDim.x + threadIdx.x;
    if (e < E) atomicAdd(&cnt[cols[e]], 1);
}

__global__ __launch_bounds__(1024) void k_scan(const int* __restrict__ cnt, int* __restrict__ rowptr, int N) {
    const int T = 1024;
    int t = threadIdx.x;
    int C = (N + T - 1) / T;
    int b = t * C, e = min(b + C, N);
    int sum = 0;
    for (int i = b; i < e; ++i) sum += cnt[i];
    __shared__ int ls[T];
    ls[t] = sum;
    __syncthreads();
    for (int off = 1; off < T; off <<= 1) {
        int v = (t >= off) ? ls[t - off] : 0;
        __syncthreads();
        ls[t] += v;
        __syncthreads();
    }
    int running = ls[t] - sum;  // exclusive base
    for (int i = b; i < e; ++i) {
        int c = cnt[i];
        rowptr[i] = running;
        running += c;
    }
    if (b < N && e == N) rowptr[N] = running;
}

// SEQ: permute ea rows into CSR order (both gate passes then read sequentially, no eid)
template <bool SEQ>
__global__ void k_scatter(const int* __restrict__ rows, const int* __restrict__ cols,
                          const float* __restrict__ ea,
                          const int* __restrict__ rowptr, int* __restrict__ cur,
                          int* __restrict__ erow, int* __restrict__ eid,
                          float* __restrict__ eap, int E) {
    int e = blockIdx.x * blockDim.x + threadIdx.x;
    if (e >= E) return;
    int c = cols[e];
    int p = rowptr[c] + atomicAdd(&cur[c], 1);
    erow[p] = rows[e];
    if (SEQ) {
        const float4* src = reinterpret_cast<const float4*>(ea + (size_t)e * ED);
        float4 v0 = src[0], v1 = src[1], v2 = src[2], v3 = src[3];
        float4* dst = reinterpret_cast<float4*>(eap + (size_t)p * ED);
        dst[0] = v0; dst[1] = v1; dst[2] = v2; dst[3] = v3;
    } else {
        eid[p] = e;
    }
}

// ---------------- gather: agg[n] = x[n] + sum_{in-edges} x[row]  (wave per node, no atomics) ----------------
template <int CIN>
__global__ void k_gather(const float* __restrict__ x, const int* __restrict__ rowptr,
                         const int* __restrict__ erow, float* __restrict__ agg, int N) {
    int lane = threadIdx.x & 63;
    int wid = (blockIdx.x * blockDim.x + threadIdx.x) >> 6;
    int nw = (gridDim.x * blockDim.x) >> 6;
    int chunk = (N + nw - 1) / nw;
    int n0 = wid * chunk, n1 = min(N, n0 + chunk);
    for (int n = n0; n < n1; ++n) {
        int s = rowptr[n], t = rowptr[n + 1];
        if (CIN == 64) {
            float acc = x[(size_t)n * 64 + lane];
            int i = s;
            for (; i + 3 < t; i += 4) {
                int r0 = erow[i], r1 = erow[i + 1], r2 = erow[i + 2], r3 = erow[i + 3];
                float x0 = x[(size_t)r0 * 64 + lane];
                float x1 = x[(size_t)r1 * 64 + lane];
                float x2 = x[(size_t)r2 * 64 + lane];
                float x3 = x[(size_t)r3 * 64 + lane];
                acc += (x0 + x1) + (x2 + x3);
            }
            for (; i < t; ++i) acc += x[(size_t)erow[i] * 64 + lane];
            agg[(size_t)n * H + lane] = acc;
        } else {
            int c = lane & 31, half = lane >> 5;
            float acc = half ? 0.f : x[(size_t)n * 32 + c];
            int i = s + half;
            for (; i + 2 < t; i += 4) {
                int r0 = erow[i], r1 = erow[i + 2];
                float x0 = x[(size_t)r0 * 32 + c];
                float x1 = x[(size_t)r1 * 32 + c];
                acc += x0 + x1;
            }
            if (i < t) acc += x[(size_t)erow[i] * 32 + c];
            acc += __shfl_xor(acc, 32);
            if (half == 0) agg[(size_t)n * H + c] = acc;
        }
    }
}

// ---------------- node matmuls: pre = (agg/deg)@Wl + bl + x@Wr ; u = pre@Wg_top + bg ----------------
template <int CIN>
__global__ void k_node_mm(const float* __restrict__ xin, const float* __restrict__ agg,
                          const int* __restrict__ rowptr,
                          const float* __restrict__ Wl, const float* __restrict__ bl,
                          const float* __restrict__ Wr,
                          const float* __restrict__ Wg, const float* __restrict__ bg,
                          float* __restrict__ pre, float* __restrict__ u, int N) {
    int n = blockIdx.x * blockDim.x + threadIdx.x;
    if (n >= N) return;
    float out[H];
#pragma unroll
    for (int j = 0; j < H; ++j) out[j] = bl[j];
    float invdeg = 1.0f / (float)(rowptr[n + 1] - rowptr[n] + 1);
    const float* ar = agg + (size_t)n * H;
    const float* xr = xin + (size_t)n * CIN;
    for (int k = 0; k < CIN; ++k) {
        float ak = ar[k] * invdeg;
        float xk = xr[k];
        const float* wl = Wl + k * H;
        const float* wr = Wr + k * H;
#pragma unroll
        for (int j = 0; j < H; ++j) out[j] += ak * wl[j] + xk * wr[j];
    }
    float* prow = pre + (size_t)n * H;
#pragma unroll
    for (int j4 = 0; j4 < H / 4; ++j4)
        reinterpret_cast<float4*>(prow)[j4] = make_float4(out[j4*4+0], out[j4*4+1], out[j4*4+2], out[j4*4+3]);
    // u = out @ Wg_top + bg  (re-read own row to avoid dynamic register indexing)
    float ua[H];
#pragma unroll
    for (int j = 0; j < H; ++j) ua[j] = bg[j];
    for (int m = 0; m < H; ++m) {
        float om = prow[m];
        const float* wg = Wg + m * H;
#pragma unroll
        for (int j = 0; j < H; ++j) ua[j] += om * wg[j];
    }
    float* urow = u + (size_t)n * H;
#pragma unroll
    for (int j4 = 0; j4 < H / 4; ++j4)
        reinterpret_cast<float4*>(urow)[j4] = make_float4(ua[j4*4+0], ua[j4*4+1], ua[j4*4+2], ua[j4*4+3]);
}

// ---------------- gate + self-contrib + add + batch stats (wave per node, weights in regs) ----------------
// SEQ: ea rows pre-permuted to CSR order (sequential reads); else indirect via eid.
template <bool SEQ>
__global__ __launch_bounds__(256, 4) void k_gate(
        const int* __restrict__ rowptr, const int* __restrict__ eid,
        const float* __restrict__ eap,
        const float* __restrict__ WeT, const float* __restrict__ WeGT,
        const float* __restrict__ be, const float* __restrict__ dv,
        const float* __restrict__ ets, const float* __restrict__ vs,
        const float* __restrict__ u, float* __restrict__ pre,
        float* __restrict__ s1, float* __restrict__ s2, int N) {
    int lane = threadIdx.x & 63;
    int wv = threadIdx.x >> 6;  // 0..3
    int wid = (blockIdx.x << 2) | wv;
    int nw = gridDim.x << 2;
    float wt[ED], wg[ED];
#pragma unroll
    for (int k = 0; k < ED; ++k) { wt[k] = WeT[lane * ED + k]; wg[k] = WeGT[lane * ED + k]; }
    float be_l = be[lane], dv_l = dv[lane], ets_l = ets[lane], vs_l = vs[lane];
    float s = 0.f, ss = 0.f;
    int chunk = (N + nw - 1) / nw;
    int n0 = wid * chunk, n1 = min(N, n0 + chunk);
    for (int n = n0; n < n1; ++n) {
        float u_l = u[(size_t)n * H + lane];
        float acc = sigm(u_l + vs_l) * ets_l;  // folded self-loop contribution
        int s0 = rowptr[n], t0 = rowptr[n + 1];
        int i = s0;
        for (; i + 1 < t0; i += 2) {
            const float4 *p0, *p1;
            if (SEQ) {
                p0 = reinterpret_cast<const float4*>(eap + (size_t)i * ED);
                p1 = p0 + 4;
            } else {
                p0 = reinterpret_cast<const float4*>(eap + (size_t)eid[i] * ED);
                p1 = reinterpret_cast<const float4*>(eap + (size_t)eid[i + 1] * ED);
            }
            float4 a0 = p0[0], a1 = p0[1], a2 = p0[2], a3 = p0[3];
            float4 b0 = p1[0], b1 = p1[1], b2 = p1[2], b3 = p1[3];
            float ea0[ED] = {a0.x,a0.y,a0.z,a0.w, a1.x,a1.y,a1.z,a1.w,
                             a2.x,a2.y,a2.z,a2.w, a3.x,a3.y,a3.z,a3.w};
            float ea1[ED] = {b0.x,b0.y,b0.z,b0.w, b1.x,b1.y,b1.z,b1.w,
                             b2.x,b2.y,b2.z,b2.w, b3.x,b3.y,b3.z,b3.w};
            float et0 = be_l, v0 = dv_l, et1 = be_l, v1 = dv_l;
#pragma unroll
            for (int k = 0; k < ED; ++k) {
                et0 += ea0[k] * wt[k]; v0 += ea0[k] * wg[k];
                et1 += ea1[k] * wt[k]; v1 += ea1[k] * wg[k];
            }
            acc += sigm(u_l + v0) * et0 + sigm(u_l + v1) * et1;
        }
        if (i < t0) {
            const float4* p0 = SEQ ? reinterpret_cast<const float4*>(eap + (size_t)i * ED)
                                   : reinterpret_cast<const float4*>(eap + (size_t)eid[i] * ED);
            float4 a0 = p0[0], a1 = p0[1], a2 = p0[2], a3 = p0[3];
            float ea0[ED] = {a0.x,a0.y,a0.z,a0.w, a1.x,a1.y,a1.z,a1.w,
                             a2.x,a2.y,a2.z,a2.w, a3.x,a3.y,a3.z,a3.w};
            float et0 = be_l, v0 = dv_l;
#pragma unroll
            for (int k = 0; k < ED; ++k) { et0 += ea0[k] * wt[k]; v0 += ea0[k] * wg[k]; }
            acc += sigm(u_l + v0) * et0;
        }
        size_t idx = (size_t)n * H + lane;
        float tval = pre[idx] + acc;
        pre[idx] = tval;
        s += tval; ss += tval * tval;
    }
    __shared__ float ls[2][4][H];
    ls[0][wv][lane] = s; ls[1][wv][lane] = ss;
    __syncthreads();
    if (threadIdx.x < H) {
        float a = ls[0][0][lane] + ls[0][1][lane] + ls[0][2][lane] + ls[0][3][lane];
        float b = ls[1][0][lane] + ls[1][1][lane] + ls[1][2][lane] + ls[1][3][lane];
        atomicAdd(&s1[lane], a);
        atomicAdd(&s2[lane], b);
    }
}

// ---------------- finalize stats -> mu_s = a*mean, rsig ----------------
__global__ void k_finalize(const float* __restrict__ s1, const float* __restrict__ s2,
                           const float* __restrict__ avec, float* __restrict__ mu_s,
                           float* __restrict__ rsig, float Ninv) {
    int j = threadIdx.x;
    float m1 = s1[j] * Ninv, m2 = s2[j] * Ninv;
    float a = avec ? avec[j] : 1.0f;
    float var = m2 - 2.f * a * m1 * m1 + a * a * m1 * m1;
    mu_s[j] = a * m1;
    rsig[j] = rsqrtf(var + EPSV);
}

// ---------------- out = relu(scale*(gamma*(in-mu_s)*rsig + beta)) (+ optional stats) ----------------
template <bool STATS>
__global__ void k_apply(const float* __restrict__ in, float* __restrict__ outb,
                        const float* __restrict__ mu_s, const float* __restrict__ rsig,
                        const float* __restrict__ gamma, const float* __restrict__ beta,
                        float scale, float* __restrict__ s1, float* __restrict__ s2, int N) {
    int j = threadIdx.x, ty = threadIdx.y;
    float mm = mu_s[j], rs = rsig[j], gm = gamma[j], bt = beta[j];
    float s = 0.f, ss = 0.f;
    for (int n = blockIdx.x * 4 + ty; n < N; n += gridDim.x * 4) {
        size_t idx = (size_t)n * H + j;
        float v = (in[idx] - mm) * rs * gm + bt;
        v = fmaxf(scale * v, 0.f);
        outb[idx] = v;
        if (STATS) { s += v; ss += v * v; }
    }
    if (STATS) {
        __shared__ float ls[2][4][H];
        ls[0][ty][j] = s; ls[1][ty][j] = ss;
        __syncthreads();
        if (ty == 0) {
            float a = ls[0][0][j] + ls[0][1][j] + ls[0][2][j] + ls[0][3][j];
            float b = ls[1][0][j] + ls[1][1][j] + ls[1][2][j] + ls[1][3][j];
            atomicAdd(&s1[j], a);
            atomicAdd(&s2[j], b);
        }
    }
}

// ---------------- final linear: d_out = hg @ lin_W + lin_b ----------------
__global__ void k_final(const float* __restrict__ hg, const float* __restrict__ W,
                        const float* __restrict__ b, float* __restrict__ outp, int N) {
    int n = blockIdx.x * blockDim.x + threadIdx.x;
    if (n >= N) return;
    float o[CO];
#pragma unroll
    for (int t = 0; t < CO; ++t) o[t] = b[t];
    const float4* hr = reinterpret_cast<const float4*>(hg + (size_t)n * H);
    for (int m4 = 0; m4 < H / 4; ++m4) {
        float4 h4 = hr[m4];
#pragma unroll
        for (int t = 0; t < CO; ++t) {
            o[t] += h4.x * W[(m4*4+0) * CO + t];
            o[t] += h4.y * W[(m4*4+1) * CO + t];
            o[t] += h4.z * W[(m4*4+2) * CO + t];
            o[t] += h4.w * W[(m4*4+3) * CO + t];
        }
    }
    float* orow = outp + (size_t)n * CO;
#pragma unroll
    for (int t4 = 0; t4 < CO / 4; ++t4)
        reinterpret_cast<float4*>(orow)[t4] = make_float4(o[t4*4+0], o[t4*4+1], o[t4*4+2], o[t4*4+3]);
}

extern "C" void kernel_launch(void* const* d_in, const int* in_sizes, int n_in,
                              void* d_out, int out_size, void* d_ws, size_t ws_size,
                              hipStream_t stream) {
    const float* x     = (const float*)d_in[0];
    const int*   ei    = (const int*)d_in[1];
    const float* ea    = (const float*)d_in[2];
    const float* l1_Wl = (const float*)d_in[3];  const float* l1_bl = (const float*)d_in[4];
    const float* l1_Wr = (const float*)d_in[5];  const float* l1_We = (const float*)d_in[6];
    const float* l1_be = (const float*)d_in[7];  const float* l1_Wg = (const float*)d_in[8];
    const float* l1_bg = (const float*)d_in[9];  const float* l1_bng= (const float*)d_in[10];
    const float* l1_bnb= (const float*)d_in[11];
    const float* l2_Wl = (const float*)d_in[12]; const float* l2_bl = (const float*)d_in[13];
    const float* l2_Wr = (const float*)d_in[14]; const float* l2_We = (const float*)d_in[15];
    const float* l2_be = (const float*)d_in[16]; const float* l2_Wg = (const float*)d_in[17];
    const float* l2_bg = (const float*)d_in[18]; const float* l2_bng= (const float*)d_in[19];
    const float* l2_bnb= (const float*)d_in[20];
    const float* gn1_g = (const float*)d_in[21]; const float* gn1_b = (const float*)d_in[22];
    const float* gn1_a = (const float*)d_in[23];
    const float* gn2_g = (const float*)d_in[24]; const float* gn2_b = (const float*)d_in[25];
    const float* gn2_a = (const float*)d_in[26];
    const float* lin_W = (const float*)d_in[27]; const float* lin_b = (const float*)d_in[28];

    const int N = in_sizes[0] / 32;
    const int E = in_sizes[1] / 2;
    const int* rows = ei;
    const int* cols = ei + E;

    float* w     = (float*)d_ws;
    float* WeT1  = w;         float* WeGT1 = w + 1024;
    float* WeT2  = w + 2048;  float* WeGT2 = w + 3072;
    float* ets1  = w + 4096;  float* vs1   = w + 4160;  float* dv1 = w + 4224;
    float* ets2  = w + 4288;  float* vs2   = w + 4352;  float* dv2 = w + 4416;
    float* stats = w + 4480;  // 4 sets of (s1[64], s2[64])
    float* norm  = w + 4992;  // 4 sets of (mu_s[64], rsig[64])

    int* ip     = (int*)(w + 8192);
    int* rowptr = ip;                 // N+1
    int* cnt    = ip + (N + 1);       // N
    int* cur    = cnt + N;            // N
    int* erow   = cur + N;            // E
    int* eid    = erow + E;           // E (only used in fallback mode)

    size_t NB = (size_t)N * H;
    // seq mode: erow end -> eap[E*ED] -> 3 node buffers
    size_t ofs_seq = (((size_t)(8192 + 3 * (size_t)N + 1 + (size_t)E) * 4) + 255) & ~(size_t)255;
    size_t need_seq = ofs_seq + ((size_t)E * ED + 3 * NB) * 4;
    // fallback: eid kept, no eap
    size_t ofs_fb = (((size_t)(8192 + 3 * (size_t)N + 1 + 2 * (size_t)E) * 4) + 255) & ~(size_t)255;
    bool seq = ws_size >= need_seq;

    float* eap; float* B0;
    if (seq) {
        eap = (float*)((char*)d_ws + ofs_seq);
        B0 = eap + (size_t)E * ED;
    } else {
        eap = nullptr;
        B0 = (float*)((char*)d_ws + ofs_fb);
    }
    float* B1 = B0 + NB;
    float* B2 = B1 + NB;

    const float Ninv = 1.0f / (float)N;
    dim3 rb(64, 4);
    int egrid = (E + 255) / 256;
    int ggrid = 2048;  // gather: 8192 waves
    int tgrid = 2048;  // gate: 8192 waves (4 waves/SIMD resident via launch_bounds)
    int ngrid = (N + 255) / 256;

    k_prep<<<1, 64, 0, stream>>>(l1_We, l1_be, l1_Wg, l2_We, l2_be, l2_Wg, w);

    // ---- CSR build (by destination col); seq mode also permutes ea into CSR order ----
    k_zero2<<<(N + 255) / 256, 256, 0, stream>>>(cnt, cur, N);
    k_count<<<egrid, 256, 0, stream>>>(cols, cnt, E);
    k_scan<<<1, 1024, 0, stream>>>(cnt, rowptr, N);
    if (seq)
        k_scatter<true><<<egrid, 256, 0, stream>>>(rows, cols, ea, rowptr, cur, erow, eid, eap, E);
    else
        k_scatter<false><<<egrid, 256, 0, stream>>>(rows, cols, ea, rowptr, cur, erow, eid, eap, E);

    // ---- layer 1 (CIN=32) ----
    k_gather<32><<<ggrid, 256, 0, stream>>>(x, rowptr, erow, B0, N);
    k_node_mm<32><<<ngrid, 256, 0, stream>>>(x, B0, rowptr, l1_Wl, l1_bl, l1_Wr, l1_Wg, l1_bg,
                                             B1, B2, N);
    if (seq)
        k_gate<true><<<tgrid, 256, 0, stream>>>(rowptr, eid, eap, WeT1, WeGT1, l1_be, dv1, ets1, vs1,
                                                B2, B1, stats + 0, stats + 64, N);
    else
        k_gate<false><<<tgrid, 256, 0, stream>>>(rowptr, eid, ea, WeT1, WeGT1, l1_be, dv1, ets1, vs1,
                                                 B2, B1, stats + 0, stats + 64, N);
    k_finalize<<<1, 64, 0, stream>>>(stats + 0, stats + 64, nullptr, norm + 0, norm + 64, Ninv);
    k_apply<true><<<256, rb, 0, stream>>>(B1, B0, norm + 0, norm + 64, l1_bng, l1_bnb, 2.0f,
                                          stats + 128, stats + 192, N);
    k_finalize<<<1, 64, 0, stream>>>(stats + 128, stats + 192, gn1_a, norm + 128, norm + 192, Ninv);
    k_apply<false><<<256, rb, 0, stream>>>(B0, B2, norm + 128, norm + 192, gn1_g, gn1_b, 1.0f,
                                           nullptr, nullptr, N);

    // ---- layer 2 (CIN=64), h = B2 ----
    k_gather<64><<<ggrid, 256, 0, stream>>>(B2, rowptr, erow, B0, N);
    k_node_mm<64><<<ngrid, 256, 0, stream>>>(B2, B0, rowptr, l2_Wl, l2_bl, l2_Wr, l2_Wg, l2_bg,
                                             B1, B2, N);  // u written in-place over h (safe: row-local)
    if (seq)
        k_gate<true><<<tgrid, 256, 0, stream>>>(rowptr, eid, eap, WeT2, WeGT2, l2_be, dv2, ets2, vs2,
                                                B2, B1, stats + 256, stats + 320, N);
    else
        k_gate<false><<<tgrid, 256, 0, stream>>>(rowptr, eid, ea, WeT2, WeGT2, l2_be, dv2, ets2, vs2,
                                                 B2, B1, stats + 256, stats + 320, N);
    k_finalize<<<1, 64, 0, stream>>>(stats + 256, stats + 320, nullptr, norm + 256, norm + 320, Ninv);
    k_apply<true><<<256, rb, 0, stream>>>(B1, B0, norm + 256, norm + 320, l2_bng, l2_bnb, 2.0f,
                                          stats + 384, stats + 448, N);
    k_finalize<<<1, 64, 0, stream>>>(stats + 384, stats + 448, gn2_a, norm + 384, norm + 448, Ninv);
    k_apply<false><<<256, rb, 0, stream>>>(B0, B2, norm + 384, norm + 448, gn2_g, gn2_b, 1.0f,
                                           nullptr, nullptr, N);

    k_final<<<ngrid, 256, 0, stream>>>(B2, lin_W, lin_b, (float*)d_out, N);
}

// Round 4
// 1283.933 us; speedup vs baseline: 14.5895x; 1.1352x over previous
//
#include <hip/hip_runtime.h>
#include <hip/hip_fp16.h>
#include <math.h>
#include <stdint.h>

#define H 64
#define ED 16
#define CO 16
static constexpr float EPSV = 1e-5f;

__device__ __forceinline__ float sigm(float z) { return 1.0f / (1.0f + __expf(-z)); }

// ---------------- prep: transposed/combined weights, self-loop consts, zero stats ----------------
// ws float layout (const area, 8192 floats):
//   0: WeT1[64*16]  1024: WeGT1[64*16]  2048: WeT2  3072: WeGT2
//   4096: ets1[64] 4160: vs1[64] 4224: dv1[64]
//   4288: ets2[64] 4352: vs2[64] 4416: dv2[64]
//   4480: stats[4][2][64]
__global__ void k_prep(const float* __restrict__ We1, const float* __restrict__ be1, const float* __restrict__ Wg1,
                       const float* __restrict__ We2, const float* __restrict__ be2, const float* __restrict__ Wg2,
                       float* __restrict__ ws) {
    int j = threadIdx.x;  // 0..63
    for (int l = 0; l < 2; ++l) {
        const float* We = l ? We2 : We1;
        const float* be = l ? be2 : be1;
        const float* Wg = l ? Wg2 : Wg1;
        float* WeT  = ws + (l ? 2048 : 0);
        float* WeGT = ws + (l ? 3072 : 1024);
        float* ets  = ws + (l ? 4288 : 4096);
        float* vs   = ws + (l ? 4352 : 4160);
        float* dv   = ws + (l ? 4416 : 4224);
        float et = be[j];
        for (int k = 0; k < ED; ++k) { float v = We[k * H + j]; WeT[j * ED + k] = v; et += v; }
        ets[j] = et;                                   // ea_t for self-loop (ea = ones)
        float d = 0.f;
        for (int m = 0; m < H; ++m) d += be[m] * Wg[(H + m) * H + j];
        dv[j] = d;                                     // be @ Wg_bot
        float vsum = d;
        for (int k = 0; k < ED; ++k) {
            float acc = 0.f;
            for (int m = 0; m < H; ++m) acc += We[k * H + m] * Wg[(H + m) * H + j];
            WeGT[j * ED + k] = acc;                    // (We @ Wg_bot)^T
            vsum += acc;
        }
        vs[j] = vsum;                                  // v for self-loop
    }
    for (int s = 0; s < 8; ++s) ws[4480 + s * 64 + j] = 0.f;  // zero all stats
}

// ---------------- CSR build ----------------
__global__ void k_count(const int* __restrict__ cols, int* __restrict__ cnt, int E) {
    int e = blockIdx.x * blockDim.x + threadIdx.x;
    if (e < E) atomicAdd(&cnt[cols[e]], 1);
}

__global__ __launch_bounds__(1024) void k_scan1(const int* __restrict__ cnt, int* __restrict__ bs, int N) {
    __shared__ int ls[1024];
    int t = threadIdx.x;
    int i = blockIdx.x * 1024 + t;
    ls[t] = (i < N) ? cnt[i] : 0;
    __syncthreads();
    for (int off = 512; off > 0; off >>= 1) {
        if (t < off) ls[t] += ls[t + off];
        __syncthreads();
    }
    if (t == 0) bs[blockIdx.x] = ls[0];
}

__global__ __launch_bounds__(1024) void k_scan2(int* __restrict__ bs, int SB) {
    __shared__ int ls[1024];
    int t = threadIdx.x;
    int v = (t < SB) ? bs[t] : 0;
    ls[t] = v;
    __syncthreads();
    for (int off = 1; off < 1024; off <<= 1) {
        int x = (t >= off) ? ls[t - off] : 0;
        __syncthreads();
        ls[t] += x;
        __syncthreads();
    }
    if (t < SB) bs[t] = ls[t] - v;  // exclusive
}

__global__ __launch_bounds__(1024) void k_scan3(const int* __restrict__ cnt, const int* __restrict__ bs,
                                                int* __restrict__ rowptr, int N, int E) {
    __shared__ int ls[1024];
    int t = threadIdx.x;
    int i = blockIdx.x * 1024 + t;
    int v = (i < N) ? cnt[i] : 0;
    ls[t] = v;
    __syncthreads();
    for (int off = 1; off < 1024; off <<= 1) {
        int x = (t >= off) ? ls[t - off] : 0;
        __syncthreads();
        ls[t] += x;
        __syncthreads();
    }
    if (i < N) rowptr[i] = bs[blockIdx.x] + ls[t] - v;  // exclusive prefix
    if (i == 0) rowptr[N] = E;
}

// ---------------- scatter: CSR edge lists; ea permuted into CSR order as f16 ----------------
__global__ void k_scatter(const int* __restrict__ rows, const int* __restrict__ cols,
                          const float* __restrict__ ea,
                          const int* __restrict__ rowptr, int* __restrict__ cur,
                          int* __restrict__ erow, __half* __restrict__ eap, int E) {
    int e = blockIdx.x * blockDim.x + threadIdx.x;
    if (e >= E) return;
    int c = cols[e];
    int p = rowptr[c] + atomicAdd(&cur[c], 1);
    erow[p] = rows[e];
    const float4* src = reinterpret_cast<const float4*>(ea + (size_t)e * ED);
    float4 v0 = src[0], v1 = src[1], v2 = src[2], v3 = src[3];
    __half2 hh[8];
    hh[0] = __floats2half2_rn(v0.x, v0.y); hh[1] = __floats2half2_rn(v0.z, v0.w);
    hh[2] = __floats2half2_rn(v1.x, v1.y); hh[3] = __floats2half2_rn(v1.z, v1.w);
    hh[4] = __floats2half2_rn(v2.x, v2.y); hh[5] = __floats2half2_rn(v2.z, v2.w);
    hh[6] = __floats2half2_rn(v3.x, v3.y); hh[7] = __floats2half2_rn(v3.z, v3.w);
    const int4* o = reinterpret_cast<const int4*>(hh);
    int4* dst = reinterpret_cast<int4*>(eap + (size_t)p * ED);
    dst[0] = o[0]; dst[1] = o[1];
}

// ---------------- edge-balanced node range for wave w of nw ----------------
__device__ __forceinline__ void node_range(const int* __restrict__ rowptr, int N, int Etot,
                                           int w, int nw, int& n0, int& n1) {
    long t0 = (long)Etot * w / nw, t1 = (long)Etot * (w + 1) / nw;
    int lo = 0, hi = N;
    while (lo < hi) { int mid = (lo + hi) >> 1; if (rowptr[mid] < (int)t0) lo = mid + 1; else hi = mid; }
    n0 = lo;
    hi = N;
    while (lo < hi) { int mid = (lo + hi) >> 1; if (rowptr[mid] < (int)t1) lo = mid + 1; else hi = mid; }
    n1 = (w == nw - 1) ? N : lo;
}

// ---------------- gather: agg[n] = T(x[n]) + sum_in T(x[row]); T = optional relu(A*v+B) (GraphNorm fold) ----
template <int CIN, bool GN>
__global__ __launch_bounds__(256) void k_gather(const float* __restrict__ x, const int* __restrict__ rowptr,
                         const int* __restrict__ erow, float* __restrict__ agg,
                         const float* __restrict__ s1, const float* __restrict__ s2,
                         const float* __restrict__ gng, const float* __restrict__ gnb,
                         const float* __restrict__ gna, float Ninv, int N, int Etot) {
    int lane = threadIdx.x & 63;
    int w = (blockIdx.x * blockDim.x + threadIdx.x) >> 6;
    int nw = (gridDim.x * blockDim.x) >> 6;
    float A = 1.f, B = 0.f;
    if (GN) {
        float mu = s1[lane] * Ninv, m2 = s2[lane] * Ninv, a = gna[lane];
        float var = m2 - 2.f * a * mu * mu + a * a * mu * mu;
        A = gng[lane] * rsqrtf(var + EPSV);
        B = gnb[lane] - A * a * mu;
    }
    int n0, n1;
    node_range(rowptr, N, Etot, w, nw, n0, n1);
    for (int n = n0; n < n1; ++n) {
        int s = rowptr[n], te = rowptr[n + 1];
        if (CIN == 64) {
            float raw = x[(size_t)n * 64 + lane];
            float acc = GN ? fmaxf(fmaf(A, raw, B), 0.f) : raw;
            int i = s;
            for (; i + 3 < te; i += 4) {
                int r0 = erow[i], r1 = erow[i + 1], r2 = erow[i + 2], r3 = erow[i + 3];
                float x0 = x[(size_t)r0 * 64 + lane];
                float x1 = x[(size_t)r1 * 64 + lane];
                float x2 = x[(size_t)r2 * 64 + lane];
                float x3 = x[(size_t)r3 * 64 + lane];
                if (GN) {
                    x0 = fmaxf(fmaf(A, x0, B), 0.f); x1 = fmaxf(fmaf(A, x1, B), 0.f);
                    x2 = fmaxf(fmaf(A, x2, B), 0.f); x3 = fmaxf(fmaf(A, x3, B), 0.f);
                }
                acc += (x0 + x1) + (x2 + x3);
            }
            for (; i < te; ++i) {
                float xv = x[(size_t)erow[i] * 64 + lane];
                if (GN) xv = fmaxf(fmaf(A, xv, B), 0.f);
                acc += xv;
            }
            agg[(size_t)n * H + lane] = acc;
        } else {
            int c = lane & 31, half = lane >> 5;
            float acc = half ? 0.f : x[(size_t)n * 32 + c];
            int i = s + half;
            for (; i + 6 < te; i += 8) {
                int r0 = erow[i], r1 = erow[i + 2], r2 = erow[i + 4], r3 = erow[i + 6];
                float x0 = x[(size_t)r0 * 32 + c];
                float x1 = x[(size_t)r1 * 32 + c];
                float x2 = x[(size_t)r2 * 32 + c];
                float x3 = x[(size_t)r3 * 32 + c];
                acc += (x0 + x1) + (x2 + x3);
            }
            for (; i < te; i += 2) acc += x[(size_t)erow[i] * 32 + c];
            acc += __shfl_xor(acc, 32);
            if (half == 0) agg[(size_t)n * H + c] = acc;
        }
    }
}

// ---------------- node matmuls: pre = (agg/deg)@Wl + bl + T(x)@Wr ; u = pre@Wg_top + bg ----------------
template <int CIN, bool GN>
__global__ __launch_bounds__(256) void k_node_mm(const float* __restrict__ xin, const float* __restrict__ agg,
                          const int* __restrict__ rowptr,
                          const float* __restrict__ Wl, const float* __restrict__ bl,
                          const float* __restrict__ Wr,
                          const float* __restrict__ Wg, const float* __restrict__ bg,
                          const float* __restrict__ s1, const float* __restrict__ s2,
                          const float* __restrict__ gng, const float* __restrict__ gnb,
                          const float* __restrict__ gna, float Ninv,
                          float* __restrict__ pre, float* __restrict__ u, int N) {
    __shared__ float As[H], Bs[H];
    if (GN) {
        if (threadIdx.x < H) {
            int j = threadIdx.x;
            float mu = s1[j] * Ninv, m2 = s2[j] * Ninv, a = gna[j];
            float var = m2 - 2.f * a * mu * mu + a * a * mu * mu;
            float A = gng[j] * rsqrtf(var + EPSV);
            As[j] = A; Bs[j] = gnb[j] - A * a * mu;
        }
        __syncthreads();
    }
    int n = blockIdx.x * blockDim.x + threadIdx.x;
    if (n >= N) return;
    float out[H];
#pragma unroll
    for (int j = 0; j < H; ++j) out[j] = bl[j];
    float invdeg = 1.0f / (float)(rowptr[n + 1] - rowptr[n] + 1);
    const float* ar = agg + (size_t)n * H;
    const float* xr = xin + (size_t)n * CIN;
    for (int k = 0; k < CIN; ++k) {
        float ak = ar[k] * invdeg;
        float xk = xr[k];
        if (GN) xk = fmaxf(fmaf(As[k], xk, Bs[k]), 0.f);
        const float* wl = Wl + k * H;
        const float* wr = Wr + k * H;
#pragma unroll
        for (int j = 0; j < H; ++j) out[j] += ak * wl[j] + xk * wr[j];
    }
    float* prow = pre + (size_t)n * H;
#pragma unroll
    for (int j4 = 0; j4 < H / 4; ++j4)
        reinterpret_cast<float4*>(prow)[j4] = make_float4(out[j4*4+0], out[j4*4+1], out[j4*4+2], out[j4*4+3]);
    float ua[H];
#pragma unroll
    for (int j = 0; j < H; ++j) ua[j] = bg[j];
    for (int m = 0; m < H; ++m) {
        float om = prow[m];
        const float* wg = Wg + m * H;
#pragma unroll
        for (int j = 0; j < H; ++j) ua[j] += om * wg[j];
    }
    float* urow = u + (size_t)n * H;
#pragma unroll
    for (int j4 = 0; j4 < H / 4; ++j4)
        reinterpret_cast<float4*>(urow)[j4] = make_float4(ua[j4*4+0], ua[j4*4+1], ua[j4*4+2], ua[j4*4+3]);
}

// ---------------- gate edge term: 2 dots of f16 ea row with fp32 weight rows ----------------
__device__ __forceinline__ float edge_term(int4 a, int4 b, const float* wt, const float* wg,
                                           float be_l, float dv_l, float u_l) {
    float et = be_l, v = dv_l;
    int ua[8] = {a.x, a.y, a.z, a.w, b.x, b.y, b.z, b.w};
#pragma unroll
    for (int q = 0; q < 8; ++q) {
        __half2 h = *reinterpret_cast<__half2*>(&ua[q]);
        float2 f = __half22float2(h);
        et += f.x * wt[2*q] + f.y * wt[2*q+1];
        v  += f.x * wg[2*q] + f.y * wg[2*q+1];
    }
    return sigm(u_l + v) * et;
}

// ---------------- gate + self-contrib + add + batch stats (wave per node, edge-balanced) ----------------
__global__ __launch_bounds__(256) void k_gate(
        const int* __restrict__ rowptr, const __half* __restrict__ eap,
        const float* __restrict__ WeT, const float* __restrict__ WeGT,
        const float* __restrict__ be, const float* __restrict__ dv,
        const float* __restrict__ ets, const float* __restrict__ vs,
        const float* __restrict__ u, float* __restrict__ pre,
        float* __restrict__ s1, float* __restrict__ s2, int N, int Etot) {
    int lane = threadIdx.x & 63;
    int wv = threadIdx.x >> 6;
    int w = (blockIdx.x << 2) | wv;
    int nw = gridDim.x << 2;
    float wt[ED], wg[ED];
#pragma unroll
    for (int k = 0; k < ED; ++k) { wt[k] = WeT[lane * ED + k]; wg[k] = WeGT[lane * ED + k]; }
    float be_l = be[lane], dv_l = dv[lane], ets_l = ets[lane], vs_l = vs[lane];
    int n0, n1;
    node_range(rowptr, N, Etot, w, nw, n0, n1);
    float s = 0.f, ss = 0.f;
    for (int n = n0; n < n1; ++n) {
        float u_l = u[(size_t)n * H + lane];
        float acc = sigm(u_l + vs_l) * ets_l;  // folded self-loop contribution
        int i = rowptr[n], te = rowptr[n + 1];
        for (; i + 3 < te; i += 4) {
            const int4* p = reinterpret_cast<const int4*>(eap + (size_t)i * ED);
            int4 d0 = p[0], d1 = p[1], d2 = p[2], d3 = p[3];
            int4 d4 = p[4], d5 = p[5], d6 = p[6], d7 = p[7];
            acc += edge_term(d0, d1, wt, wg, be_l, dv_l, u_l);
            acc += edge_term(d2, d3, wt, wg, be_l, dv_l, u_l);
            acc += edge_term(d4, d5, wt, wg, be_l, dv_l, u_l);
            acc += edge_term(d6, d7, wt, wg, be_l, dv_l, u_l);
        }
        for (; i < te; ++i) {
            const int4* p = reinterpret_cast<const int4*>(eap + (size_t)i * ED);
            acc += edge_term(p[0], p[1], wt, wg, be_l, dv_l, u_l);
        }
        size_t idx = (size_t)n * H + lane;
        float tval = pre[idx] + acc;
        pre[idx] = tval;
        s += tval; ss += tval * tval;
    }
    __shared__ float ls[2][4][H];
    ls[0][wv][lane] = s; ls[1][wv][lane] = ss;
    __syncthreads();
    if (threadIdx.x < H) {
        float a = ls[0][0][lane] + ls[0][1][lane] + ls[0][2][lane] + ls[0][3][lane];
        float b = ls[1][0][lane] + ls[1][1][lane] + ls[1][2][lane] + ls[1][3][lane];
        atomicAdd(&s1[lane], a);
        atomicAdd(&s2[lane], b);
    }
}

// ---------------- apply: h = relu(2*bn(t)) (bn finalized in-block) + GraphNorm stats ----------------
__global__ void k_apply(const float* __restrict__ in, float* __restrict__ outb,
                        const float* __restrict__ bng, const float* __restrict__ bnb,
                        const float* __restrict__ s1b, const float* __restrict__ s2b,
                        float* __restrict__ s1g, float* __restrict__ s2g, float Ninv, int N) {
    int j = threadIdx.x, ty = threadIdx.y;
    __shared__ float As[H], Bs[H];
    if (ty == 0) {
        float mu = s1b[j] * Ninv, var = s2b[j] * Ninv - mu * mu;
        float r = rsqrtf(var + EPSV);
        float A = 2.f * bng[j] * r;
        As[j] = A; Bs[j] = 2.f * (bnb[j] - bng[j] * r * mu);
    }
    __syncthreads();
    float A = As[j], B = Bs[j];
    float s = 0.f, ss = 0.f;
    for (int n = blockIdx.x * 4 + ty; n < N; n += gridDim.x * 4) {
        size_t idx = (size_t)n * H + j;
        float v = fmaxf(fmaf(A, in[idx], B), 0.f);
        outb[idx] = v;
        s += v; ss += v * v;
    }
    __shared__ float ls[2][4][H];
    ls[0][ty][j] = s; ls[1][ty][j] = ss;
    __syncthreads();
    if (ty == 0) {
        float a = ls[0][0][j] + ls[0][1][j] + ls[0][2][j] + ls[0][3][j];
        float b = ls[1][0][j] + ls[1][1][j] + ls[1][2][j] + ls[1][3][j];
        atomicAdd(&s1g[j], a);
        atomicAdd(&s2g[j], b);
    }
}

// ---------------- final: out = relu(gn2(h)) @ lin_W + lin_b (gn2 finalized in-block) ----------------
__global__ __launch_bounds__(256) void k_final(const float* __restrict__ hraw, const float* __restrict__ W,
                        const float* __restrict__ bias,
                        const float* __restrict__ s1, const float* __restrict__ s2,
                        const float* __restrict__ gng, const float* __restrict__ gnb,
                        const float* __restrict__ gna, float Ninv,
                        float* __restrict__ outp, int N) {
    __shared__ float As[H], Bs[H];
    if (threadIdx.x < H) {
        int j = threadIdx.x;
        float mu = s1[j] * Ninv, m2 = s2[j] * Ninv, a = gna[j];
        float var = m2 - 2.f * a * mu * mu + a * a * mu * mu;
        float A = gng[j] * rsqrtf(var + EPSV);
        As[j] = A; Bs[j] = gnb[j] - A * a * mu;
    }
    __syncthreads();
    int n = blockIdx.x * blockDim.x + threadIdx.x;
    if (n >= N) return;
    float o[CO];
#pragma unroll
    for (int t = 0; t < CO; ++t) o[t] = bias[t];
    const float4* hr = reinterpret_cast<const float4*>(hraw + (size_t)n * H);
    for (int m4 = 0; m4 < H / 4; ++m4) {
        float4 h4 = hr[m4];
        h4.x = fmaxf(fmaf(As[m4*4+0], h4.x, Bs[m4*4+0]), 0.f);
        h4.y = fmaxf(fmaf(As[m4*4+1], h4.y, Bs[m4*4+1]), 0.f);
        h4.z = fmaxf(fmaf(As[m4*4+2], h4.z, Bs[m4*4+2]), 0.f);
        h4.w = fmaxf(fmaf(As[m4*4+3], h4.w, Bs[m4*4+3]), 0.f);
#pragma unroll
        for (int t = 0; t < CO; ++t) {
            o[t] += h4.x * W[(m4*4+0) * CO + t];
            o[t] += h4.y * W[(m4*4+1) * CO + t];
            o[t] += h4.z * W[(m4*4+2) * CO + t];
            o[t] += h4.w * W[(m4*4+3) * CO + t];
        }
    }
    float* orow = outp + (size_t)n * CO;
#pragma unroll
    for (int t4 = 0; t4 < CO / 4; ++t4)
        reinterpret_cast<float4*>(orow)[t4] = make_float4(o[t4*4+0], o[t4*4+1], o[t4*4+2], o[t4*4+3]);
}

extern "C" void kernel_launch(void* const* d_in, const int* in_sizes, int n_in,
                              void* d_out, int out_size, void* d_ws, size_t ws_size,
                              hipStream_t stream) {
    const float* x     = (const float*)d_in[0];
    const int*   ei    = (const int*)d_in[1];
    const float* ea    = (const float*)d_in[2];
    const float* l1_Wl = (const float*)d_in[3];  const float* l1_bl = (const float*)d_in[4];
    const float* l1_Wr = (const float*)d_in[5];  const float* l1_We = (const float*)d_in[6];
    const float* l1_be = (const float*)d_in[7];  const float* l1_Wg = (const float*)d_in[8];
    const float* l1_bg = (const float*)d_in[9];  const float* l1_bng= (const float*)d_in[10];
    const float* l1_bnb= (const float*)d_in[11];
    const float* l2_Wl = (const float*)d_in[12]; const float* l2_bl = (const float*)d_in[13];
    const float* l2_Wr = (const float*)d_in[14]; const float* l2_We = (const float*)d_in[15];
    const float* l2_be = (const float*)d_in[16]; const float* l2_Wg = (const float*)d_in[17];
    const float* l2_bg = (const float*)d_in[18]; const float* l2_bng= (const float*)d_in[19];
    const float* l2_bnb= (const float*)d_in[20];
    const float* gn1_g = (const float*)d_in[21]; const float* gn1_b = (const float*)d_in[22];
    const float* gn1_a = (const float*)d_in[23];
    const float* gn2_g = (const float*)d_in[24]; const float* gn2_b = (const float*)d_in[25];
    const float* gn2_a = (const float*)d_in[26];
    const float* lin_W = (const float*)d_in[27]; const float* lin_b = (const float*)d_in[28];

    const int N = in_sizes[0] / 32;
    const int E = in_sizes[1] / 2;
    const int* rows = ei;
    const int* cols = ei + E;

    float* w     = (float*)d_ws;
    float* WeT1  = w;         float* WeGT1 = w + 1024;
    float* WeT2  = w + 2048;  float* WeGT2 = w + 3072;
    float* ets1  = w + 4096;  float* vs1   = w + 4160;  float* dv1 = w + 4224;
    float* ets2  = w + 4288;  float* vs2   = w + 4352;  float* dv2 = w + 4416;
    float* stats = w + 4480;  // 4 sets of (s1[64], s2[64])

    int* ip     = (int*)(w + 8192);
    int* rowptr = ip;                 // N+1
    int* cnt    = ip + (N + 1);       // N
    int* cur    = cnt + N;            // N (contiguous with cnt for one memset)
    int* bs     = cur + N;            // scan block sums (<=1024)
    int* erow   = bs + 1024;          // E

    uintptr_t pa = (uintptr_t)(erow + E);
    pa = (pa + 255) & ~(uintptr_t)255;
    __half* eap = (__half*)pa;        // E*16 halves
    uintptr_t pb = (uintptr_t)(eap + (size_t)E * ED);
    pb = (pb + 255) & ~(uintptr_t)255;
    float* B0 = (float*)pb;
    size_t NB = (size_t)N * H;
    float* B1 = B0 + NB;
    float* B2 = B1 + NB;
    float* B3 = B2 + NB;

    const float Ninv = 1.0f / (float)N;
    dim3 rb(64, 4);
    int egrid = (E + 255) / 256;
    int ngrid = (N + 255) / 256;
    int wgrid = 3072;                 // 12288 waves, edge-balanced
    const int SB = (N + 1023) >> 10;  // scan blocks (<=1024)

    k_prep<<<1, 64, 0, stream>>>(l1_We, l1_be, l1_Wg, l2_We, l2_be, l2_Wg, w);

    // ---- CSR build (by destination col); ea permuted to CSR order as f16 ----
    hipMemsetAsync(cnt, 0, sizeof(int) * 2 * (size_t)N, stream);
    k_count<<<egrid, 256, 0, stream>>>(cols, cnt, E);
    k_scan1<<<SB, 1024, 0, stream>>>(cnt, bs, N);
    k_scan2<<<1, 1024, 0, stream>>>(bs, SB);
    k_scan3<<<SB, 1024, 0, stream>>>(cnt, bs, rowptr, N, E);
    k_scatter<<<egrid, 256, 0, stream>>>(rows, cols, ea, rowptr, cur, erow, eap, E);

    // ---- layer 1 (CIN=32) ----
    k_gather<32, false><<<wgrid, 256, 0, stream>>>(x, rowptr, erow, B0,
                                                   nullptr, nullptr, nullptr, nullptr, nullptr, 0.f, N, E);
    k_node_mm<32, false><<<ngrid, 256, 0, stream>>>(x, B0, rowptr, l1_Wl, l1_bl, l1_Wr, l1_Wg, l1_bg,
                                                    nullptr, nullptr, nullptr, nullptr, nullptr, 0.f,
                                                    B1, B2, N);
    k_gate<<<wgrid, 256, 0, stream>>>(rowptr, eap, WeT1, WeGT1, l1_be, dv1, ets1, vs1,
                                      B2, B1, stats + 0, stats + 64, N, E);
    k_apply<<<256, rb, 0, stream>>>(B1, B3, l1_bng, l1_bnb, stats + 0, stats + 64,
                                    stats + 128, stats + 192, Ninv, N);

    // ---- layer 2 (CIN=64); gn1 folded into readers of B3 ----
    k_gather<64, true><<<wgrid, 256, 0, stream>>>(B3, rowptr, erow, B0,
                                                  stats + 128, stats + 192, gn1_g, gn1_b, gn1_a, Ninv, N, E);
    k_node_mm<64, true><<<ngrid, 256, 0, stream>>>(B3, B0, rowptr, l2_Wl, l2_bl, l2_Wr, l2_Wg, l2_bg,
                                                   stats + 128, stats + 192, gn1_g, gn1_b, gn1_a, Ninv,
                                                   B1, B2, N);
    k_gate<<<wgrid, 256, 0, stream>>>(rowptr, eap, WeT2, WeGT2, l2_be, dv2, ets2, vs2,
                                      B2, B1, stats + 256, stats + 320, N, E);
    k_apply<<<256, rb, 0, stream>>>(B1, B0, l2_bng, l2_bnb, stats + 256, stats + 320,
                                    stats + 384, stats + 448, Ninv, N);

    // ---- final: gn2 fold + linear ----
    k_final<<<ngrid, 256, 0, stream>>>(B0, lin_W, lin_b, stats + 384, stats + 448,
                                       gn2_g, gn2_b, gn2_a, Ninv, (float*)d_out, N);
}

// Round 5
// 941.753 us; speedup vs baseline: 19.8905x; 1.3633x over previous
//
#include <hip/hip_runtime.h>
#include <hip/hip_fp16.h>
#include <math.h>
#include <stdint.h>

#define H 64
#define ED 16
#define CO 16
#define WGRID 3072
#define NWAVES (WGRID * 4)
static constexpr float EPSV = 1e-5f;

typedef _Float16 h2v __attribute__((ext_vector_type(2)));

__device__ __forceinline__ float sigm(float z) { return 1.0f / (1.0f + __expf(-z)); }

__device__ __forceinline__ h2v as_h2(int x) { union { int i; h2v h; } u; u.i = x; return u.h; }

__device__ __forceinline__ int pack2(float a, float b) {
    __half2 h = __floats2half2_rn(a, b);
    return *reinterpret_cast<int*>(&h);
}

// ---------------- prep: packed-f16 gate weights, self-loop consts, zero stats ----------------
// ws float layout (const area, 8192 floats):
//   0: wth1[512] (int-packed half2)  512: wgh1[512]  1024: wth2[512]  1536: wgh2[512]
//   2048: ets1[64] 2112: vs1[64] 2176: dv1[64]
//   2240: ets2[64] 2304: vs2[64] 2368: dv2[64]
//   2432: stats[8][64]
__global__ void k_prep(const float* __restrict__ We1, const float* __restrict__ be1, const float* __restrict__ Wg1,
                       const float* __restrict__ We2, const float* __restrict__ be2, const float* __restrict__ Wg2,
                       float* __restrict__ ws) {
    int j = threadIdx.x;  // 0..63
    for (int l = 0; l < 2; ++l) {
        const float* We = l ? We2 : We1;
        const float* be = l ? be2 : be1;
        const float* Wg = l ? Wg2 : Wg1;
        int* wth = (int*)(ws + (l ? 1024 : 0));
        int* wgh = (int*)(ws + (l ? 1536 : 512));
        float* ets = ws + 2048 + l * 192;
        float* vs  = ws + 2112 + l * 192;
        float* dv  = ws + 2176 + l * 192;
        float wt[ED], wg[ED];
        float et = be[j];
        for (int k = 0; k < ED; ++k) { wt[k] = We[k * H + j]; et += wt[k]; }
        ets[j] = et;                                   // ea_t for self-loop (ea = ones)
        float d = 0.f;
        for (int m = 0; m < H; ++m) d += be[m] * Wg[(H + m) * H + j];
        dv[j] = d;                                     // be @ Wg_bot
        float vsum = d;
        for (int k = 0; k < ED; ++k) {
            float acc = 0.f;
            for (int m = 0; m < H; ++m) acc += We[k * H + m] * Wg[(H + m) * H + j];
            wg[k] = acc;                               // (We @ Wg_bot)^T
            vsum += acc;
        }
        vs[j] = vsum;                                  // v for self-loop
        for (int q = 0; q < 8; ++q) {
            wth[j * 8 + q] = pack2(wt[2 * q], wt[2 * q + 1]);
            wgh[j * 8 + q] = pack2(wg[2 * q], wg[2 * q + 1]);
        }
    }
    for (int s = 0; s < 8; ++s) ws[2432 + s * 64 + j] = 0.f;  // zero all stats
}

// ---------------- CSR build ----------------
__global__ void k_count(const int* __restrict__ cols, int* __restrict__ cnt, int E) {
    int e = blockIdx.x * blockDim.x + threadIdx.x;
    if (e < E) atomicAdd(&cnt[cols[e]], 1);
}

__global__ __launch_bounds__(1024) void k_scan1(const int* __restrict__ cnt, int* __restrict__ bs, int N) {
    __shared__ int ls[1024];
    int t = threadIdx.x;
    int i = blockIdx.x * 1024 + t;
    ls[t] = (i < N) ? cnt[i] : 0;
    __syncthreads();
    for (int off = 512; off > 0; off >>= 1) {
        if (t < off) ls[t] += ls[t + off];
        __syncthreads();
    }
    if (t == 0) bs[blockIdx.x] = ls[0];
}

__global__ __launch_bounds__(1024) void k_scan2(int* __restrict__ bs, int SB) {
    __shared__ int ls[1024];
    int t = threadIdx.x;
    int v = (t < SB) ? bs[t] : 0;
    ls[t] = v;
    __syncthreads();
    for (int off = 1; off < 1024; off <<= 1) {
        int x = (t >= off) ? ls[t - off] : 0;
        __syncthreads();
        ls[t] += x;
        __syncthreads();
    }
    if (t < SB) bs[t] = ls[t] - v;  // exclusive
}

__global__ __launch_bounds__(1024) void k_scan3(const int* __restrict__ cnt, const int* __restrict__ bs,
                                                int* __restrict__ rowptr, int N, int E) {
    __shared__ int ls[1024];
    int t = threadIdx.x;
    int i = blockIdx.x * 1024 + t;
    int v = (i < N) ? cnt[i] : 0;
    ls[t] = v;
    __syncthreads();
    for (int off = 1; off < 1024; off <<= 1) {
        int x = (t >= off) ? ls[t - off] : 0;
        __syncthreads();
        ls[t] += x;
        __syncthreads();
    }
    if (i < N) rowptr[i] = bs[blockIdx.x] + ls[t] - v;  // exclusive prefix
    if (i == 0) rowptr[N] = E;
}

// ---------------- wave ranges: ranges[w] = lower_bound(rowptr, E*w/nw) (done once, reused 4x) ---------
__global__ void k_ranges(const int* __restrict__ rowptr, int* __restrict__ ranges, int N, int E, int nw) {
    int w = blockIdx.x * blockDim.x + threadIdx.x;
    if (w > nw) return;
    if (w == nw) { ranges[nw] = N; return; }
    int t0 = (int)((long)E * w / nw);
    int lo = 0, hi = N;
    while (lo < hi) { int mid = (lo + hi) >> 1; if (rowptr[mid] < t0) lo = mid + 1; else hi = mid; }
    ranges[w] = lo;
}

// ---------------- scatter: CSR edge lists; ea permuted into CSR order as f16 ----------------
__global__ void k_scatter(const int* __restrict__ rows, const int* __restrict__ cols,
                          const float* __restrict__ ea,
                          const int* __restrict__ rowptr, int* __restrict__ cur,
                          int* __restrict__ erow, __half* __restrict__ eap, int E) {
    int e = blockIdx.x * blockDim.x + threadIdx.x;
    if (e >= E) return;
    int c = cols[e];
    int p = rowptr[c] + atomicAdd(&cur[c], 1);
    erow[p] = rows[e];
    const float4* src = reinterpret_cast<const float4*>(ea + (size_t)e * ED);
    float4 v0 = src[0], v1 = src[1], v2 = src[2], v3 = src[3];
    int hh[8];
    hh[0] = pack2(v0.x, v0.y); hh[1] = pack2(v0.z, v0.w);
    hh[2] = pack2(v1.x, v1.y); hh[3] = pack2(v1.z, v1.w);
    hh[4] = pack2(v2.x, v2.y); hh[5] = pack2(v2.z, v2.w);
    hh[6] = pack2(v3.x, v3.y); hh[7] = pack2(v3.z, v3.w);
    const int4* o = reinterpret_cast<const int4*>(hh);
    int4* dst = reinterpret_cast<int4*>(eap + (size_t)p * ED);
    dst[0] = o[0]; dst[1] = o[1];
}

// ---------------- gather: agg[n] = T(x[n]) + sum_in T(x[row]); T = optional relu(A*v+B) (gn1 fold) ----
template <int CIN, bool GN>
__global__ __launch_bounds__(256) void k_gather(const float* __restrict__ x, const int* __restrict__ rowptr,
                         const int* __restrict__ ranges,
                         const int* __restrict__ erow, float* __restrict__ agg,
                         const float* __restrict__ s1, const float* __restrict__ s2,
                         const float* __restrict__ gng, const float* __restrict__ gnb,
                         const float* __restrict__ gna, float Ninv, int N) {
    int lane = threadIdx.x & 63;
    int w = (blockIdx.x * blockDim.x + threadIdx.x) >> 6;
    float A = 1.f, B = 0.f;
    if (GN) {
        float mu = s1[lane] * Ninv, m2 = s2[lane] * Ninv, a = gna[lane];
        float var = m2 - 2.f * a * mu * mu + a * a * mu * mu;
        A = gng[lane] * rsqrtf(var + EPSV);
        B = gnb[lane] - A * a * mu;
    }
    int n0 = ranges[w], n1 = ranges[w + 1];
    for (int n = n0; n < n1; ++n) {
        int s = rowptr[n], te = rowptr[n + 1];
        if (CIN == 64) {
            float raw = x[(size_t)n * 64 + lane];
            float acc = GN ? fmaxf(fmaf(A, raw, B), 0.f) : raw;
            int i = s;
            for (; i + 7 < te; i += 8) {
                int r0 = erow[i],     r1 = erow[i + 1], r2 = erow[i + 2], r3 = erow[i + 3];
                int r4 = erow[i + 4], r5 = erow[i + 5], r6 = erow[i + 6], r7 = erow[i + 7];
                float x0 = x[(size_t)r0 * 64 + lane], x1 = x[(size_t)r1 * 64 + lane];
                float x2 = x[(size_t)r2 * 64 + lane], x3 = x[(size_t)r3 * 64 + lane];
                float x4 = x[(size_t)r4 * 64 + lane], x5 = x[(size_t)r5 * 64 + lane];
                float x6 = x[(size_t)r6 * 64 + lane], x7 = x[(size_t)r7 * 64 + lane];
                if (GN) {
                    x0 = fmaxf(fmaf(A, x0, B), 0.f); x1 = fmaxf(fmaf(A, x1, B), 0.f);
                    x2 = fmaxf(fmaf(A, x2, B), 0.f); x3 = fmaxf(fmaf(A, x3, B), 0.f);
                    x4 = fmaxf(fmaf(A, x4, B), 0.f); x5 = fmaxf(fmaf(A, x5, B), 0.f);
                    x6 = fmaxf(fmaf(A, x6, B), 0.f); x7 = fmaxf(fmaf(A, x7, B), 0.f);
                }
                acc += ((x0 + x1) + (x2 + x3)) + ((x4 + x5) + (x6 + x7));
            }
            for (; i < te; ++i) {
                float xv = x[(size_t)erow[i] * 64 + lane];
                if (GN) xv = fmaxf(fmaf(A, xv, B), 0.f);
                acc += xv;
            }
            agg[(size_t)n * H + lane] = acc;
        } else {
            int c = lane & 31, half = lane >> 5;
            float acc = half ? 0.f : x[(size_t)n * 32 + c];
            int i = s + half;
            for (; i + 6 < te; i += 8) {
                int r0 = erow[i], r1 = erow[i + 2], r2 = erow[i + 4], r3 = erow[i + 6];
                float x0 = x[(size_t)r0 * 32 + c];
                float x1 = x[(size_t)r1 * 32 + c];
                float x2 = x[(size_t)r2 * 32 + c];
                float x3 = x[(size_t)r3 * 32 + c];
                acc += (x0 + x1) + (x2 + x3);
            }
            for (; i < te; i += 2) acc += x[(size_t)erow[i] * 32 + c];
            acc += __shfl_xor(acc, 32);
            if (half == 0) agg[(size_t)n * H + c] = acc;
        }
    }
}

// ---------------- node matmuls: pre = (agg/deg)@Wl + bl + T(x)@Wr ; u = pre@Wg_top + bg ----------------
template <int CIN, bool GN>
__global__ __launch_bounds__(256) void k_node_mm(const float* __restrict__ xin, const float* __restrict__ agg,
                          const int* __restrict__ rowptr,
                          const float* __restrict__ Wl, const float* __restrict__ bl,
                          const float* __restrict__ Wr,
                          const float* __restrict__ Wg, const float* __restrict__ bg,
                          const float* __restrict__ s1, const float* __restrict__ s2,
                          const float* __restrict__ gng, const float* __restrict__ gnb,
                          const float* __restrict__ gna, float Ninv,
                          float* __restrict__ pre, float* __restrict__ u, int N) {
    __shared__ float As[H], Bs[H];
    if (GN) {
        if (threadIdx.x < H) {
            int j = threadIdx.x;
            float mu = s1[j] * Ninv, m2 = s2[j] * Ninv, a = gna[j];
            float var = m2 - 2.f * a * mu * mu + a * a * mu * mu;
            float A = gng[j] * rsqrtf(var + EPSV);
            As[j] = A; Bs[j] = gnb[j] - A * a * mu;
        }
        __syncthreads();
    }
    int n = blockIdx.x * blockDim.x + threadIdx.x;
    if (n >= N) return;
    float out[H];
#pragma unroll
    for (int j = 0; j < H; ++j) out[j] = bl[j];
    float invdeg = 1.0f / (float)(rowptr[n + 1] - rowptr[n] + 1);
    const float* ar = agg + (size_t)n * H;
    const float* xr = xin + (size_t)n * CIN;
    for (int k = 0; k < CIN; ++k) {
        float ak = ar[k] * invdeg;
        float xk = xr[k];
        if (GN) xk = fmaxf(fmaf(As[k], xk, Bs[k]), 0.f);
        const float* wl = Wl + k * H;
        const float* wr = Wr + k * H;
#pragma unroll
        for (int j = 0; j < H; ++j) out[j] += ak * wl[j] + xk * wr[j];
    }
    float* prow = pre + (size_t)n * H;
#pragma unroll
    for (int j4 = 0; j4 < H / 4; ++j4)
        reinterpret_cast<float4*>(prow)[j4] = make_float4(out[j4*4+0], out[j4*4+1], out[j4*4+2], out[j4*4+3]);
    float ua[H];
#pragma unroll
    for (int j = 0; j < H; ++j) ua[j] = bg[j];
    for (int m = 0; m < H; ++m) {
        float om = prow[m];
        const float* wg = Wg + m * H;
#pragma unroll
        for (int j = 0; j < H; ++j) ua[j] += om * wg[j];
    }
    float* urow = u + (size_t)n * H;
#pragma unroll
    for (int j4 = 0; j4 < H / 4; ++j4)
        reinterpret_cast<float4*>(urow)[j4] = make_float4(ua[j4*4+0], ua[j4*4+1], ua[j4*4+2], ua[j4*4+3]);
}

// ---------------- gate edge term: 2 dots via v_dot2_f32_f16 (f16 ea row x f16 weight rows) ----------
__device__ __forceinline__ float edge_term(const int4& a, const int4& b,
                                           const h2v* wt, const h2v* wg,
                                           float be_l, float dv_l, float u_l) {
    int ua[8] = {a.x, a.y, a.z, a.w, b.x, b.y, b.z, b.w};
    float et = be_l, v = dv_l;
#pragma unroll
    for (int q = 0; q < 8; ++q) {
        h2v e = as_h2(ua[q]);
        et = __builtin_amdgcn_fdot2(e, wt[q], et, false);
        v  = __builtin_amdgcn_fdot2(e, wg[q], v, false);
    }
    return sigm(u_l + v) * et;
}

// ---------------- gate + self-contrib + add + batch stats (wave per node, edge-balanced) ----------------
__global__ __launch_bounds__(256) void k_gate(
        const int* __restrict__ rowptr, const int* __restrict__ ranges,
        const __half* __restrict__ eap,
        const int* __restrict__ wth, const int* __restrict__ wgh,
        const float* __restrict__ be, const float* __restrict__ dv,
        const float* __restrict__ ets, const float* __restrict__ vs,
        const float* __restrict__ u, float* __restrict__ pre,
        float* __restrict__ s1, float* __restrict__ s2, int N) {
    int lane = threadIdx.x & 63;
    int wv = threadIdx.x >> 6;
    int w = (blockIdx.x << 2) | wv;
    h2v wt[8], wg[8];
#pragma unroll
    for (int q = 0; q < 8; ++q) { wt[q] = as_h2(wth[lane * 8 + q]); wg[q] = as_h2(wgh[lane * 8 + q]); }
    float be_l = be[lane], dv_l = dv[lane], ets_l = ets[lane], vs_l = vs[lane];
    int n0 = ranges[w], n1 = ranges[w + 1];
    float s = 0.f, ss = 0.f;
    for (int n = n0; n < n1; ++n) {
        float u_l = u[(size_t)n * H + lane];
        float acc = sigm(u_l + vs_l) * ets_l;  // folded self-loop contribution
        int i = rowptr[n], te = rowptr[n + 1];
        for (; i + 3 < te; i += 4) {
            const int4* p = reinterpret_cast<const int4*>(eap + (size_t)i * ED);
            int4 d0 = p[0], d1 = p[1], d2 = p[2], d3 = p[3];
            int4 d4 = p[4], d5 = p[5], d6 = p[6], d7 = p[7];
            acc += edge_term(d0, d1, wt, wg, be_l, dv_l, u_l);
            acc += edge_term(d2, d3, wt, wg, be_l, dv_l, u_l);
            acc += edge_term(d4, d5, wt, wg, be_l, dv_l, u_l);
            acc += edge_term(d6, d7, wt, wg, be_l, dv_l, u_l);
        }
        for (; i < te; ++i) {
            const int4* p = reinterpret_cast<const int4*>(eap + (size_t)i * ED);
            int4 d0 = p[0], d1 = p[1];
            acc += edge_term(d0, d1, wt, wg, be_l, dv_l, u_l);
        }
        size_t idx = (size_t)n * H + lane;
        float tval = pre[idx] + acc;
        pre[idx] = tval;
        s += tval; ss += tval * tval;
    }
    __shared__ float ls[2][4][H];
    ls[0][wv][lane] = s; ls[1][wv][lane] = ss;
    __syncthreads();
    if (threadIdx.x < H) {
        float a = ls[0][0][lane] + ls[0][1][lane] + ls[0][2][lane] + ls[0][3][lane];
        float b = ls[1][0][lane] + ls[1][1][lane] + ls[1][2][lane] + ls[1][3][lane];
        atomicAdd(&s1[lane], a);
        atomicAdd(&s2[lane], b);
    }
}

// ---------------- apply: h = relu(2*bn(t)) (bn finalized in-block) + GraphNorm stats ----------------
__global__ void k_apply(const float* __restrict__ in, float* __restrict__ outb,
                        const float* __restrict__ bng, const float* __restrict__ bnb,
                        const float* __restrict__ s1b, const float* __restrict__ s2b,
                        float* __restrict__ s1g, float* __restrict__ s2g, float Ninv, int N) {
    int j = threadIdx.x, ty = threadIdx.y;
    __shared__ float As[H], Bs[H];
    if (ty == 0) {
        float mu = s1b[j] * Ninv, var = s2b[j] * Ninv - mu * mu;
        float r = rsqrtf(var + EPSV);
        float A = 2.f * bng[j] * r;
        As[j] = A; Bs[j] = 2.f * (bnb[j] - bng[j] * r * mu);
    }
    __syncthreads();
    float A = As[j], B = Bs[j];
    float s = 0.f, ss = 0.f;
    for (int n = blockIdx.x * 4 + ty; n < N; n += gridDim.x * 4) {
        size_t idx = (size_t)n * H + j;
        float v = fmaxf(fmaf(A, in[idx], B), 0.f);
        outb[idx] = v;
        s += v; ss += v * v;
    }
    __shared__ float ls[2][4][H];
    ls[0][ty][j] = s; ls[1][ty][j] = ss;
    __syncthreads();
    if (ty == 0) {
        float a = ls[0][0][j] + ls[0][1][j] + ls[0][2][j] + ls[0][3][j];
        float b = ls[1][0][j] + ls[1][1][j] + ls[1][2][j] + ls[1][3][j];
        atomicAdd(&s1g[j], a);
        atomicAdd(&s2g[j], b);
    }
}

// ---------------- final: out = relu(gn2(h)) @ lin_W + lin_b (gn2 finalized in-block) ----------------
__global__ __launch_bounds__(256) void k_final(const float* __restrict__ hraw, const float* __restrict__ W,
                        const float* __restrict__ bias,
                        const float* __restrict__ s1, const float* __restrict__ s2,
                        const float* __restrict__ gng, const float* __restrict__ gnb,
                        const float* __restrict__ gna, float Ninv,
                        float* __restrict__ outp, int N) {
    __shared__ float As[H], Bs[H];
    if (threadIdx.x < H) {
        int j = threadIdx.x;
        float mu = s1[j] * Ninv, m2 = s2[j] * Ninv, a = gna[j];
        float var = m2 - 2.f * a * mu * mu + a * a * mu * mu;
        float A = gng[j] * rsqrtf(var + EPSV);
        As[j] = A; Bs[j] = gnb[j] - A * a * mu;
    }
    __syncthreads();
    int n = blockIdx.x * blockDim.x + threadIdx.x;
    if (n >= N) return;
    float o[CO];
#pragma unroll
    for (int t = 0; t < CO; ++t) o[t] = bias[t];
    const float4* hr = reinterpret_cast<const float4*>(hraw + (size_t)n * H);
    for (int m4 = 0; m4 < H / 4; ++m4) {
        float4 h4 = hr[m4];
        h4.x = fmaxf(fmaf(As[m4*4+0], h4.x, Bs[m4*4+0]), 0.f);
        h4.y = fmaxf(fmaf(As[m4*4+1], h4.y, Bs[m4*4+1]), 0.f);
        h4.z = fmaxf(fmaf(As[m4*4+2], h4.z, Bs[m4*4+2]), 0.f);
        h4.w = fmaxf(fmaf(As[m4*4+3], h4.w, Bs[m4*4+3]), 0.f);
#pragma unroll
        for (int t = 0; t < CO; ++t) {
            o[t] += h4.x * W[(m4*4+0) * CO + t];
            o[t] += h4.y * W[(m4*4+1) * CO + t];
            o[t] += h4.z * W[(m4*4+2) * CO + t];
            o[t] += h4.w * W[(m4*4+3) * CO + t];
        }
    }
    float* orow = outp + (size_t)n * CO;
#pragma unroll
    for (int t4 = 0; t4 < CO / 4; ++t4)
        reinterpret_cast<float4*>(orow)[t4] = make_float4(o[t4*4+0], o[t4*4+1], o[t4*4+2], o[t4*4+3]);
}

extern "C" void kernel_launch(void* const* d_in, const int* in_sizes, int n_in,
                              void* d_out, int out_size, void* d_ws, size_t ws_size,
                              hipStream_t stream) {
    const float* x     = (const float*)d_in[0];
    const int*   ei    = (const int*)d_in[1];
    const float* ea    = (const float*)d_in[2];
    const float* l1_Wl = (const float*)d_in[3];  const float* l1_bl = (const float*)d_in[4];
    const float* l1_Wr = (const float*)d_in[5];  const float* l1_We = (const float*)d_in[6];
    const float* l1_be = (const float*)d_in[7];  const float* l1_Wg = (const float*)d_in[8];
    const float* l1_bg = (const float*)d_in[9];  const float* l1_bng= (const float*)d_in[10];
    const float* l1_bnb= (const float*)d_in[11];
    const float* l2_Wl = (const float*)d_in[12]; const float* l2_bl = (const float*)d_in[13];
    const float* l2_Wr = (const float*)d_in[14]; const float* l2_We = (const float*)d_in[15];
    const float* l2_be = (const float*)d_in[16]; const float* l2_Wg = (const float*)d_in[17];
    const float* l2_bg = (const float*)d_in[18]; const float* l2_bng= (const float*)d_in[19];
    const float* l2_bnb= (const float*)d_in[20];
    const float* gn1_g = (const float*)d_in[21]; const float* gn1_b = (const float*)d_in[22];
    const float* gn1_a = (const float*)d_in[23];
    const float* gn2_g = (const float*)d_in[24]; const float* gn2_b = (const float*)d_in[25];
    const float* gn2_a = (const float*)d_in[26];
    const float* lin_W = (const float*)d_in[27]; const float* lin_b = (const float*)d_in[28];

    const int N = in_sizes[0] / 32;
    const int E = in_sizes[1] / 2;
    const int* rows = ei;
    const int* cols = ei + E;

    float* w    = (float*)d_ws;
    int* wth1   = (int*)w;            // 512
    int* wgh1   = (int*)(w + 512);
    int* wth2   = (int*)(w + 1024);
    int* wgh2   = (int*)(w + 1536);
    float* ets1 = w + 2048; float* vs1 = w + 2112; float* dv1 = w + 2176;
    float* ets2 = w + 2240; float* vs2 = w + 2304; float* dv2 = w + 2368;
    float* stats= w + 2432;           // 8 x 64

    int* ip     = (int*)(w + 8192);
    int* rowptr = ip;                 // N+1
    int* cnt    = ip + (N + 1);       // N
    int* cur    = cnt + N;            // N (contiguous with cnt for one memset)
    int* bs     = cur + N;            // scan block sums (<=1024)
    int* ranges = bs + 1024;          // NWAVES+1 (+pad)
    int* erow   = ranges + (NWAVES + 2);  // E

    uintptr_t pa = (uintptr_t)(erow + E);
    pa = (pa + 255) & ~(uintptr_t)255;
    __half* eap = (__half*)pa;        // E*16 halves
    uintptr_t pb = (uintptr_t)(eap + (size_t)E * ED);
    pb = (pb + 255) & ~(uintptr_t)255;
    float* B0 = (float*)pb;
    size_t NB = (size_t)N * H;
    float* B1 = B0 + NB;
    float* B2 = B1 + NB;
    float* B3 = B2 + NB;

    const float Ninv = 1.0f / (float)N;
    dim3 rb(64, 4);
    int egrid = (E + 255) / 256;
    int ngrid = (N + 255) / 256;
    const int SB = (N + 1023) >> 10;  // scan blocks (<=1024)

    k_prep<<<1, 64, 0, stream>>>(l1_We, l1_be, l1_Wg, l2_We, l2_be, l2_Wg, w);

    // ---- CSR build (by destination col); ea permuted to CSR order as f16 ----
    hipMemsetAsync(cnt, 0, sizeof(int) * 2 * (size_t)N, stream);
    k_count<<<egrid, 256, 0, stream>>>(cols, cnt, E);
    k_scan1<<<SB, 1024, 0, stream>>>(cnt, bs, N);
    k_scan2<<<1, 1024, 0, stream>>>(bs, SB);
    k_scan3<<<SB, 1024, 0, stream>>>(cnt, bs, rowptr, N, E);
    k_ranges<<<(NWAVES + 256) / 256, 256, 0, stream>>>(rowptr, ranges, N, E, NWAVES);
    k_scatter<<<egrid, 256, 0, stream>>>(rows, cols, ea, rowptr, cur, erow, eap, E);

    // ---- layer 1 (CIN=32) ----
    k_gather<32, false><<<WGRID, 256, 0, stream>>>(x, rowptr, ranges, erow, B0,
                                                   nullptr, nullptr, nullptr, nullptr, nullptr, 0.f, N);
    k_node_mm<32, false><<<ngrid, 256, 0, stream>>>(x, B0, rowptr, l1_Wl, l1_bl, l1_Wr, l1_Wg, l1_bg,
                                                    nullptr, nullptr, nullptr, nullptr, nullptr, 0.f,
                                                    B1, B2, N);
    k_gate<<<WGRID, 256, 0, stream>>>(rowptr, ranges, eap, wth1, wgh1, l1_be, dv1, ets1, vs1,
                                      B2, B1, stats + 0, stats + 64, N);
    k_apply<<<256, rb, 0, stream>>>(B1, B3, l1_bng, l1_bnb, stats + 0, stats + 64,
                                    stats + 128, stats + 192, Ninv, N);

    // ---- layer 2 (CIN=64); gn1 folded into readers of B3 ----
    k_gather<64, true><<<WGRID, 256, 0, stream>>>(B3, rowptr, ranges, erow, B0,
                                                  stats + 128, stats + 192, gn1_g, gn1_b, gn1_a, Ninv, N);
    k_node_mm<64, true><<<ngrid, 256, 0, stream>>>(B3, B0, rowptr, l2_Wl, l2_bl, l2_Wr, l2_Wg, l2_bg,
                                                   stats + 128, stats + 192, gn1_g, gn1_b, gn1_a, Ninv,
                                                   B1, B2, N);
    k_gate<<<WGRID, 256, 0, stream>>>(rowptr, ranges, eap, wth2, wgh2, l2_be, dv2, ets2, vs2,
                                      B2, B1, stats + 256, stats + 320, N);
    k_apply<<<256, rb, 0, stream>>>(B1, B0, l2_bng, l2_bnb, stats + 256, stats + 320,
                                    stats + 384, stats + 448, Ninv, N);

    // ---- final: gn2 fold + linear ----
    k_final<<<ngrid, 256, 0, stream>>>(B0, lin_W, lin_b, stats + 384, stats + 448,
                                       gn2_g, gn2_b, gn2_a, Ninv, (float*)d_out, N);
}

// Round 6
// 856.159 us; speedup vs baseline: 21.8790x; 1.1000x over previous
//
#include <hip/hip_runtime.h>
#include <hip/hip_fp16.h>
#include <math.h>
#include <stdint.h>

#define H 64
#define ED 16
#define CO 16
#define WGRID 2048
#define NWAVES (WGRID * 4)
static constexpr float EPSV = 1e-5f;
static constexpr float LOG2E = 1.44269504f;

typedef _Float16 h2v __attribute__((ext_vector_type(2)));

// sigmoid with pre-scaled (log2e-folded) argument: 1/(1+2^-z)
__device__ __forceinline__ float sigm2(float z) {
    return __builtin_amdgcn_rcpf(1.0f + __builtin_amdgcn_exp2f(-z));
}

__device__ __forceinline__ h2v as_h2(int x) { union { int i; h2v h; } u; u.i = x; return u.h; }

__device__ __forceinline__ int pack2(float a, float b) {
    __half2 h = __floats2half2_rn(a, b);
    return *reinterpret_cast<int*>(&h);
}

// ---------------- prep: packed-f16 gate weights (log2e-folded gate path), self-loop consts, zero stats --
// ws float layout (const area, 8192 floats):
//   0: wth1[512] (int-packed half2)  512: wgh1[512]  1024: wth2[512]  1536: wgh2[512]
//   2048: ets1[64] 2112: vs1[64] 2176: dv1[64]
//   2240: ets2[64] 2304: vs2[64] 2368: dv2[64]
//   2432: stats[8][64]
__global__ void k_prep(const float* __restrict__ We1, const float* __restrict__ be1, const float* __restrict__ Wg1,
                       const float* __restrict__ We2, const float* __restrict__ be2, const float* __restrict__ Wg2,
                       float* __restrict__ ws) {
    int j = threadIdx.x;  // 0..63
    for (int l = 0; l < 2; ++l) {
        const float* We = l ? We2 : We1;
        const float* be = l ? be2 : be1;
        const float* Wg = l ? Wg2 : Wg1;
        int* wth = (int*)(ws + (l ? 1024 : 0));
        int* wgh = (int*)(ws + (l ? 1536 : 512));
        float* ets = ws + 2048 + l * 192;
        float* vs  = ws + 2112 + l * 192;
        float* dv  = ws + 2176 + l * 192;
        float wt[ED], wg[ED];
        float et = be[j];
        for (int k = 0; k < ED; ++k) { wt[k] = We[k * H + j]; et += wt[k]; }
        ets[j] = et;                                   // ea_t for self-loop (ea = ones)
        float d = 0.f;
        for (int m = 0; m < H; ++m) d += be[m] * Wg[(H + m) * H + j];
        float vsum = d;
        for (int k = 0; k < ED; ++k) {
            float acc = 0.f;
            for (int m = 0; m < H; ++m) acc += We[k * H + m] * Wg[(H + m) * H + j];
            wg[k] = acc;                               // (We @ Wg_bot)^T
            vsum += acc;
        }
        dv[j] = d * LOG2E;                             // log2e-folded
        vs[j] = vsum * LOG2E;
        for (int q = 0; q < 8; ++q) {
            wth[j * 8 + q] = pack2(wt[2 * q], wt[2 * q + 1]);
            wgh[j * 8 + q] = pack2(wg[2 * q] * LOG2E, wg[2 * q + 1] * LOG2E);
        }
    }
    for (int s = 0; s < 8; ++s) ws[2432 + s * 64 + j] = 0.f;  // zero all stats
}

// ---------------- CSR build ----------------
__global__ void k_count(const int* __restrict__ cols, int* __restrict__ cnt, int E) {
    int e = blockIdx.x * blockDim.x + threadIdx.x;
    if (e < E) atomicAdd(&cnt[cols[e]], 1);
}

__global__ __launch_bounds__(1024) void k_scan1(const int* __restrict__ cnt, int* __restrict__ bs, int N) {
    __shared__ int ls[1024];
    int t = threadIdx.x;
    int i = blockIdx.x * 1024 + t;
    ls[t] = (i < N) ? cnt[i] : 0;
    __syncthreads();
    for (int off = 512; off > 0; off >>= 1) {
        if (t < off) ls[t] += ls[t + off];
        __syncthreads();
    }
    if (t == 0) bs[blockIdx.x] = ls[0];
}

__global__ __launch_bounds__(1024) void k_scan2(int* __restrict__ bs, int SB) {
    __shared__ int ls[1024];
    int t = threadIdx.x;
    int v = (t < SB) ? bs[t] : 0;
    ls[t] = v;
    __syncthreads();
    for (int off = 1; off < 1024; off <<= 1) {
        int x = (t >= off) ? ls[t - off] : 0;
        __syncthreads();
        ls[t] += x;
        __syncthreads();
    }
    if (t < SB) bs[t] = ls[t] - v;  // exclusive
}

__global__ __launch_bounds__(1024) void k_scan3(const int* __restrict__ cnt, const int* __restrict__ bs,
                                                int* __restrict__ rowptr, int N, int E) {
    __shared__ int ls[1024];
    int t = threadIdx.x;
    int i = blockIdx.x * 1024 + t;
    int v = (i < N) ? cnt[i] : 0;
    ls[t] = v;
    __syncthreads();
    for (int off = 1; off < 1024; off <<= 1) {
        int x = (t >= off) ? ls[t - off] : 0;
        __syncthreads();
        ls[t] += x;
        __syncthreads();
    }
    if (i < N) rowptr[i] = bs[blockIdx.x] + ls[t] - v;  // exclusive prefix
    if (i == 0) rowptr[N] = E;
}

// ---------------- wave ranges: ranges[w] = lower_bound(rowptr, E*w/nw) (once, reused 4x) ---------
__global__ void k_ranges(const int* __restrict__ rowptr, int* __restrict__ ranges, int N, int E, int nw) {
    int w = blockIdx.x * blockDim.x + threadIdx.x;
    if (w > nw) return;
    if (w == nw) { ranges[nw] = N; return; }
    int t0 = (int)((long)E * w / nw);
    int lo = 0, hi = N;
    while (lo < hi) { int mid = (lo + hi) >> 1; if (rowptr[mid] < t0) lo = mid + 1; else hi = mid; }
    ranges[w] = lo;
}

// ---------------- scatter: CSR edge lists; ea permuted into CSR order as f16 ----------------
__global__ void k_scatter(const int* __restrict__ rows, const int* __restrict__ cols,
                          const float* __restrict__ ea,
                          const int* __restrict__ rowptr, int* __restrict__ cur,
                          int* __restrict__ erow, __half* __restrict__ eap, int E) {
    int e = blockIdx.x * blockDim.x + threadIdx.x;
    if (e >= E) return;
    int c = cols[e];
    int p = rowptr[c] + atomicAdd(&cur[c], 1);
    erow[p] = rows[e];
    const float4* src = reinterpret_cast<const float4*>(ea + (size_t)e * ED);
    float4 v0 = src[0], v1 = src[1], v2 = src[2], v3 = src[3];
    int hh[8];
    hh[0] = pack2(v0.x, v0.y); hh[1] = pack2(v0.z, v0.w);
    hh[2] = pack2(v1.x, v1.y); hh[3] = pack2(v1.z, v1.w);
    hh[4] = pack2(v2.x, v2.y); hh[5] = pack2(v2.z, v2.w);
    hh[6] = pack2(v3.x, v3.y); hh[7] = pack2(v3.z, v3.w);
    const int4* o = reinterpret_cast<const int4*>(hh);
    int4* dst = reinterpret_cast<int4*>(eap + (size_t)p * ED);
    dst[0] = o[0]; dst[1] = o[1];
}

// ---------------- gather: agg[n] = T(x[n]) + sum_in T(x[row]); T = optional relu(A*v+B) (gn1 fold) ----
template <int CIN, bool GN>
__global__ __launch_bounds__(256) void k_gather(const float* __restrict__ x, const int* __restrict__ rowptr,
                         const int* __restrict__ ranges,
                         const int* __restrict__ erow, float* __restrict__ agg,
                         const float* __restrict__ s1, const float* __restrict__ s2,
                         const float* __restrict__ gng, const float* __restrict__ gnb,
                         const float* __restrict__ gna, float Ninv, int N) {
    int lane = threadIdx.x & 63;
    int w = (blockIdx.x * blockDim.x + threadIdx.x) >> 6;
    float A = 1.f, B = 0.f;
    if (GN) {
        float mu = s1[lane] * Ninv, m2 = s2[lane] * Ninv, a = gna[lane];
        float var = m2 - 2.f * a * mu * mu + a * a * mu * mu;
        A = gng[lane] * rsqrtf(var + EPSV);
        B = gnb[lane] - A * a * mu;
    }
    int n0 = ranges[w], n1 = ranges[w + 1];
    for (int n = n0; n < n1; ++n) {
        int s = rowptr[n], te = rowptr[n + 1];
        if (CIN == 64) {
            float raw = x[(size_t)n * 64 + lane];
            float acc = GN ? fmaxf(fmaf(A, raw, B), 0.f) : raw;
            int i = s;
            for (; i + 7 < te; i += 8) {
                int r0 = erow[i],     r1 = erow[i + 1], r2 = erow[i + 2], r3 = erow[i + 3];
                int r4 = erow[i + 4], r5 = erow[i + 5], r6 = erow[i + 6], r7 = erow[i + 7];
                float x0 = x[(size_t)r0 * 64 + lane], x1 = x[(size_t)r1 * 64 + lane];
                float x2 = x[(size_t)r2 * 64 + lane], x3 = x[(size_t)r3 * 64 + lane];
                float x4 = x[(size_t)r4 * 64 + lane], x5 = x[(size_t)r5 * 64 + lane];
                float x6 = x[(size_t)r6 * 64 + lane], x7 = x[(size_t)r7 * 64 + lane];
                if (GN) {
                    x0 = fmaxf(fmaf(A, x0, B), 0.f); x1 = fmaxf(fmaf(A, x1, B), 0.f);
                    x2 = fmaxf(fmaf(A, x2, B), 0.f); x3 = fmaxf(fmaf(A, x3, B), 0.f);
                    x4 = fmaxf(fmaf(A, x4, B), 0.f); x5 = fmaxf(fmaf(A, x5, B), 0.f);
                    x6 = fmaxf(fmaf(A, x6, B), 0.f); x7 = fmaxf(fmaf(A, x7, B), 0.f);
                }
                acc += ((x0 + x1) + (x2 + x3)) + ((x4 + x5) + (x6 + x7));
            }
            for (; i < te; ++i) {
                float xv = x[(size_t)erow[i] * 64 + lane];
                if (GN) xv = fmaxf(fmaf(A, xv, B), 0.f);
                acc += xv;
            }
            agg[(size_t)n * H + lane] = acc;
        } else {
            int c = lane & 31, half = lane >> 5;
            float acc = half ? 0.f : x[(size_t)n * 32 + c];
            int i = s + half;
            for (; i + 6 < te; i += 8) {
                int r0 = erow[i], r1 = erow[i + 2], r2 = erow[i + 4], r3 = erow[i + 6];
                float x0 = x[(size_t)r0 * 32 + c];
                float x1 = x[(size_t)r1 * 32 + c];
                float x2 = x[(size_t)r2 * 32 + c];
                float x3 = x[(size_t)r3 * 32 + c];
                acc += (x0 + x1) + (x2 + x3);
            }
            for (; i < te; i += 2) acc += x[(size_t)erow[i] * 32 + c];
            acc += __shfl_xor(acc, 32);
            if (half == 0) agg[(size_t)n * H + c] = acc;
        }
    }
}

// ---------------- tiled GEMM: out[64-node blk][64] = A@W1 (+ A2@W2) + bias ----------------
// DEG: scale A rows by 1/deg at staging. GN: relu(As*v+Bs) transform on A2 at staging.
// SCALE: fold log2e into W1/bias (u-pass for sigm2).
#define MT4A(mq, aval) \
    acc[mq][0] = fmaf(aval, w1.x, acc[mq][0]); acc[mq][1] = fmaf(aval, w1.y, acc[mq][1]); \
    acc[mq][2] = fmaf(aval, w1.z, acc[mq][2]); acc[mq][3] = fmaf(aval, w1.w, acc[mq][3]);
#define MT4X(mq, aval) \
    acc[mq][0] = fmaf(aval, w2.x, acc[mq][0]); acc[mq][1] = fmaf(aval, w2.y, acc[mq][1]); \
    acc[mq][2] = fmaf(aval, w2.z, acc[mq][2]); acc[mq][3] = fmaf(aval, w2.w, acc[mq][3]);

template <int K, bool DUAL, bool GN, bool DEG, bool SCALE>
__global__ __launch_bounds__(256) void k_gemm64(
        const float* __restrict__ A, int lda,
        const float* __restrict__ A2, int lda2,
        const float* __restrict__ W1, const float* __restrict__ W2,
        const float* __restrict__ bias,
        const float* __restrict__ s1, const float* __restrict__ s2,
        const float* __restrict__ gng, const float* __restrict__ gnb,
        const float* __restrict__ gna, float Ninv,
        const int* __restrict__ rowptr,
        float* __restrict__ outp, int N) {
    __shared__ float W1s[K * 64];
    __shared__ float W2s[DUAL ? K * 64 : 64];
    __shared__ float aTc[16][68];
    __shared__ float xTc[DUAL ? 16 : 1][68];
    __shared__ float As[64], Bs[64], invd[64];
    int tid = threadIdx.x;
    for (int idx = tid; idx < K * 64; idx += 256) {
        float wv = W1[idx];
        W1s[idx] = SCALE ? wv * LOG2E : wv;
        if (DUAL) W2s[idx] = W2[idx];
    }
    int nb = blockIdx.x * 64;
    if (tid < 64) {
        if (GN) {
            float mu = s1[tid] * Ninv, m2 = s2[tid] * Ninv, a = gna[tid];
            float var = m2 - 2.f * a * mu * mu + a * a * mu * mu;
            float Av = gng[tid] * rsqrtf(var + EPSV);
            As[tid] = Av; Bs[tid] = gnb[tid] - Av * a * mu;
        }
        if (DEG) {
            int n = nb + tid;
            invd[tid] = (n < N) ? 1.f / (float)(rowptr[n + 1] - rowptr[n] + 1) : 0.f;
        }
    }
    __syncthreads();
    int tm = tid >> 4, tn = tid & 15;
    int m0 = tm * 4, j0 = tn * 4;
    float acc[4][4];
#pragma unroll
    for (int jq = 0; jq < 4; ++jq) {
        float b = bias[j0 + jq];
        if (SCALE) b *= LOG2E;
#pragma unroll
        for (int mq = 0; mq < 4; ++mq) acc[mq][jq] = b;
    }
    int sn = tid >> 2;            // staging node-local 0..63
    int kq4 = (tid & 3) * 4;
    int sgnode = nb + sn;
    for (int k0 = 0; k0 < K; k0 += 16) {
        if (k0) __syncthreads();
        if (sgnode < N) {
            float4 av = *reinterpret_cast<const float4*>(A + (size_t)sgnode * lda + k0 + kq4);
            if (DEG) { float s = invd[sn]; av.x *= s; av.y *= s; av.z *= s; av.w *= s; }
            aTc[kq4 + 0][sn] = av.x; aTc[kq4 + 1][sn] = av.y;
            aTc[kq4 + 2][sn] = av.z; aTc[kq4 + 3][sn] = av.w;
            if (DUAL) {
                float4 xv = *reinterpret_cast<const float4*>(A2 + (size_t)sgnode * lda2 + k0 + kq4);
                if (GN) {
                    xv.x = fmaxf(fmaf(As[k0 + kq4 + 0], xv.x, Bs[k0 + kq4 + 0]), 0.f);
                    xv.y = fmaxf(fmaf(As[k0 + kq4 + 1], xv.y, Bs[k0 + kq4 + 1]), 0.f);
                    xv.z = fmaxf(fmaf(As[k0 + kq4 + 2], xv.z, Bs[k0 + kq4 + 2]), 0.f);
                    xv.w = fmaxf(fmaf(As[k0 + kq4 + 3], xv.w, Bs[k0 + kq4 + 3]), 0.f);
                }
                xTc[kq4 + 0][sn] = xv.x; xTc[kq4 + 1][sn] = xv.y;
                xTc[kq4 + 2][sn] = xv.z; xTc[kq4 + 3][sn] = xv.w;
            }
        } else {
            aTc[kq4 + 0][sn] = 0.f; aTc[kq4 + 1][sn] = 0.f;
            aTc[kq4 + 2][sn] = 0.f; aTc[kq4 + 3][sn] = 0.f;
            if (DUAL) {
                xTc[kq4 + 0][sn] = 0.f; xTc[kq4 + 1][sn] = 0.f;
                xTc[kq4 + 2][sn] = 0.f; xTc[kq4 + 3][sn] = 0.f;
            }
        }
        __syncthreads();
#pragma unroll
        for (int k = 0; k < 16; ++k) {
            float4 am = *reinterpret_cast<const float4*>(&aTc[k][m0]);
            float4 w1 = *reinterpret_cast<const float4*>(&W1s[(k0 + k) * 64 + j0]);
            MT4A(0, am.x) MT4A(1, am.y) MT4A(2, am.z) MT4A(3, am.w)
            if (DUAL) {
                float4 xm = *reinterpret_cast<const float4*>(&xTc[k][m0]);
                float4 w2 = *reinterpret_cast<const float4*>(&W2s[(k0 + k) * 64 + j0]);
                MT4X(0, xm.x) MT4X(1, xm.y) MT4X(2, xm.z) MT4X(3, xm.w)
            }
        }
    }
#pragma unroll
    for (int mq = 0; mq < 4; ++mq) {
        int n = nb + m0 + mq;
        if (n < N)
            *reinterpret_cast<float4*>(outp + (size_t)n * 64 + j0) =
                make_float4(acc[mq][0], acc[mq][1], acc[mq][2], acc[mq][3]);
    }
}

// ---------------- gate edge term: 2 dots via v_dot2_f32_f16 ----------
__device__ __forceinline__ float edge_term(const int4& a, const int4& b,
                                           const h2v* wt, const h2v* wg,
                                           float be_l, float dv_l, float u_l) {
    int ua[8] = {a.x, a.y, a.z, a.w, b.x, b.y, b.z, b.w};
    float et = be_l, v = dv_l;
#pragma unroll
    for (int q = 0; q < 8; ++q) {
        h2v e = as_h2(ua[q]);
        et = __builtin_amdgcn_fdot2(e, wt[q], et, false);
        v  = __builtin_amdgcn_fdot2(e, wg[q], v, false);
    }
    return sigm2(u_l + v) * et;
}

// ---------------- gate + self-contrib + add + batch stats (wave per node, edge-balanced) ----------------
__global__ __launch_bounds__(256) void k_gate(
        const int* __restrict__ rowptr, const int* __restrict__ ranges,
        const __half* __restrict__ eap,
        const int* __restrict__ wth, const int* __restrict__ wgh,
        const float* __restrict__ be, const float* __restrict__ dv,
        const float* __restrict__ ets, const float* __restrict__ vs,
        const float* __restrict__ u, float* __restrict__ pre,
        float* __restrict__ s1, float* __restrict__ s2, int N) {
    int lane = threadIdx.x & 63;
    int wv = threadIdx.x >> 6;
    int w = (blockIdx.x << 2) | wv;
    h2v wt[8], wg[8];
#pragma unroll
    for (int q = 0; q < 8; ++q) { wt[q] = as_h2(wth[lane * 8 + q]); wg[q] = as_h2(wgh[lane * 8 + q]); }
    float be_l = be[lane], dv_l = dv[lane], ets_l = ets[lane], vs_l = vs[lane];
    int n0 = ranges[w], n1 = ranges[w + 1];
    float s = 0.f, ss = 0.f;
    for (int n = n0; n < n1; ++n) {
        float u_l = u[(size_t)n * H + lane];
        float pv  = pre[(size_t)n * H + lane];
        float acc = sigm2(u_l + vs_l) * ets_l;  // folded self-loop contribution
        int i = rowptr[n], te = rowptr[n + 1];
        for (; i + 7 < te; i += 8) {
            const int4* p = reinterpret_cast<const int4*>(eap + (size_t)i * ED);
            int4 d0 = p[0],  d1 = p[1],  d2 = p[2],  d3 = p[3];
            int4 d4 = p[4],  d5 = p[5],  d6 = p[6],  d7 = p[7];
            int4 d8 = p[8],  d9 = p[9],  dA = p[10], dB = p[11];
            int4 dC = p[12], dD = p[13], dE = p[14], dF = p[15];
            acc += edge_term(d0, d1, wt, wg, be_l, dv_l, u_l);
            acc += edge_term(d2, d3, wt, wg, be_l, dv_l, u_l);
            acc += edge_term(d4, d5, wt, wg, be_l, dv_l, u_l);
            acc += edge_term(d6, d7, wt, wg, be_l, dv_l, u_l);
            acc += edge_term(d8, d9, wt, wg, be_l, dv_l, u_l);
            acc += edge_term(dA, dB, wt, wg, be_l, dv_l, u_l);
            acc += edge_term(dC, dD, wt, wg, be_l, dv_l, u_l);
            acc += edge_term(dE, dF, wt, wg, be_l, dv_l, u_l);
        }
        for (; i + 3 < te; i += 4) {
            const int4* p = reinterpret_cast<const int4*>(eap + (size_t)i * ED);
            int4 d0 = p[0], d1 = p[1], d2 = p[2], d3 = p[3];
            int4 d4 = p[4], d5 = p[5], d6 = p[6], d7 = p[7];
            acc += edge_term(d0, d1, wt, wg, be_l, dv_l, u_l);
            acc += edge_term(d2, d3, wt, wg, be_l, dv_l, u_l);
            acc += edge_term(d4, d5, wt, wg, be_l, dv_l, u_l);
            acc += edge_term(d6, d7, wt, wg, be_l, dv_l, u_l);
        }
        for (; i < te; ++i) {
            const int4* p = reinterpret_cast<const int4*>(eap + (size_t)i * ED);
            int4 d0 = p[0], d1 = p[1];
            acc += edge_term(d0, d1, wt, wg, be_l, dv_l, u_l);
        }
        float tval = pv + acc;
        pre[(size_t)n * H + lane] = tval;
        s += tval; ss += tval * tval;
    }
    __shared__ float ls[2][4][H];
    ls[0][wv][lane] = s; ls[1][wv][lane] = ss;
    __syncthreads();
    if (threadIdx.x < H) {
        float a = ls[0][0][lane] + ls[0][1][lane] + ls[0][2][lane] + ls[0][3][lane];
        float b = ls[1][0][lane] + ls[1][1][lane] + ls[1][2][lane] + ls[1][3][lane];
        atomicAdd(&s1[lane], a);
        atomicAdd(&s2[lane], b);
    }
}

// ---------------- apply: h = relu(2*bn(t)) (bn finalized in-block) + GraphNorm stats ----------------
__global__ void k_apply(const float* __restrict__ in, float* __restrict__ outb,
                        const float* __restrict__ bng, const float* __restrict__ bnb,
                        const float* __restrict__ s1b, const float* __restrict__ s2b,
                        float* __restrict__ s1g, float* __restrict__ s2g, float Ninv, int N) {
    int j = threadIdx.x, ty = threadIdx.y;
    __shared__ float As[H], Bs[H];
    if (ty == 0) {
        float mu = s1b[j] * Ninv, var = s2b[j] * Ninv - mu * mu;
        float r = rsqrtf(var + EPSV);
        float A = 2.f * bng[j] * r;
        As[j] = A; Bs[j] = 2.f * (bnb[j] - bng[j] * r * mu);
    }
    __syncthreads();
    float A = As[j], B = Bs[j];
    float s = 0.f, ss = 0.f;
    for (int n = blockIdx.x * 4 + ty; n < N; n += gridDim.x * 4) {
        size_t idx = (size_t)n * H + j;
        float v = fmaxf(fmaf(A, in[idx], B), 0.f);
        outb[idx] = v;
        s += v; ss += v * v;
    }
    __shared__ float ls[2][4][H];
    ls[0][ty][j] = s; ls[1][ty][j] = ss;
    __syncthreads();
    if (ty == 0) {
        float a = ls[0][0][j] + ls[0][1][j] + ls[0][2][j] + ls[0][3][j];
        float b = ls[1][0][j] + ls[1][1][j] + ls[1][2][j] + ls[1][3][j];
        atomicAdd(&s1g[j], a);
        atomicAdd(&s2g[j], b);
    }
}

// ---------------- final: out = relu(gn2(h)) @ lin_W + lin_b (gn2 finalized in-block) ----------------
__global__ __launch_bounds__(256) void k_final(const float* __restrict__ hraw, const float* __restrict__ W,
                        const float* __restrict__ bias,
                        const float* __restrict__ s1, const float* __restrict__ s2,
                        const float* __restrict__ gng, const float* __restrict__ gnb,
                        const float* __restrict__ gna, float Ninv,
                        float* __restrict__ outp, int N) {
    __shared__ float As[H], Bs[H];
    if (threadIdx.x < H) {
        int j = threadIdx.x;
        float mu = s1[j] * Ninv, m2 = s2[j] * Ninv, a = gna[j];
        float var = m2 - 2.f * a * mu * mu + a * a * mu * mu;
        float A = gng[j] * rsqrtf(var + EPSV);
        As[j] = A; Bs[j] = gnb[j] - A * a * mu;
    }
    __syncthreads();
    int n = blockIdx.x * blockDim.x + threadIdx.x;
    if (n >= N) return;
    float o[CO];
#pragma unroll
    for (int t = 0; t < CO; ++t) o[t] = bias[t];
    const float4* hr = reinterpret_cast<const float4*>(hraw + (size_t)n * H);
    for (int m4 = 0; m4 < H / 4; ++m4) {
        float4 h4 = hr[m4];
        h4.x = fmaxf(fmaf(As[m4*4+0], h4.x, Bs[m4*4+0]), 0.f);
        h4.y = fmaxf(fmaf(As[m4*4+1], h4.y, Bs[m4*4+1]), 0.f);
        h4.z = fmaxf(fmaf(As[m4*4+2], h4.z, Bs[m4*4+2]), 0.f);
        h4.w = fmaxf(fmaf(As[m4*4+3], h4.w, Bs[m4*4+3]), 0.f);
#pragma unroll
        for (int t = 0; t < CO; ++t) {
            o[t] += h4.x * W[(m4*4+0) * CO + t];
            o[t] += h4.y * W[(m4*4+1) * CO + t];
            o[t] += h4.z * W[(m4*4+2) * CO + t];
            o[t] += h4.w * W[(m4*4+3) * CO + t];
        }
    }
    float* orow = outp + (size_t)n * CO;
#pragma unroll
    for (int t4 = 0; t4 < CO / 4; ++t4)
        reinterpret_cast<float4*>(orow)[t4] = make_float4(o[t4*4+0], o[t4*4+1], o[t4*4+2], o[t4*4+3]);
}

extern "C" void kernel_launch(void* const* d_in, const int* in_sizes, int n_in,
                              void* d_out, int out_size, void* d_ws, size_t ws_size,
                              hipStream_t stream) {
    const float* x     = (const float*)d_in[0];
    const int*   ei    = (const int*)d_in[1];
    const float* ea    = (const float*)d_in[2];
    const float* l1_Wl = (const float*)d_in[3];  const float* l1_bl = (const float*)d_in[4];
    const float* l1_Wr = (const float*)d_in[5];  const float* l1_We = (const float*)d_in[6];
    const float* l1_be = (const float*)d_in[7];  const float* l1_Wg = (const float*)d_in[8];
    const float* l1_bg = (const float*)d_in[9];  const float* l1_bng= (const float*)d_in[10];
    const float* l1_bnb= (const float*)d_in[11];
    const float* l2_Wl = (const float*)d_in[12]; const float* l2_bl = (const float*)d_in[13];
    const float* l2_Wr = (const float*)d_in[14]; const float* l2_We = (const float*)d_in[15];
    const float* l2_be = (const float*)d_in[16]; const float* l2_Wg = (const float*)d_in[17];
    const float* l2_bg = (const float*)d_in[18]; const float* l2_bng= (const float*)d_in[19];
    const float* l2_bnb= (const float*)d_in[20];
    const float* gn1_g = (const float*)d_in[21]; const float* gn1_b = (const float*)d_in[22];
    const float* gn1_a = (const float*)d_in[23];
    const float* gn2_g = (const float*)d_in[24]; const float* gn2_b = (const float*)d_in[25];
    const float* gn2_a = (const float*)d_in[26];
    const float* lin_W = (const float*)d_in[27]; const float* lin_b = (const float*)d_in[28];

    const int N = in_sizes[0] / 32;
    const int E = in_sizes[1] / 2;
    const int* rows = ei;
    const int* cols = ei + E;

    float* w    = (float*)d_ws;
    int* wth1   = (int*)w;            // 512
    int* wgh1   = (int*)(w + 512);
    int* wth2   = (int*)(w + 1024);
    int* wgh2   = (int*)(w + 1536);
    float* ets1 = w + 2048; float* vs1 = w + 2112; float* dv1 = w + 2176;
    float* ets2 = w + 2240; float* vs2 = w + 2304; float* dv2 = w + 2368;
    float* stats= w + 2432;           // 8 x 64

    int* ip     = (int*)(w + 8192);
    int* rowptr = ip;                 // N+1
    int* cnt    = ip + (N + 1);       // N
    int* cur    = cnt + N;            // N (contiguous with cnt for one memset)
    int* bs     = cur + N;            // scan block sums (<=1024)
    int* ranges = bs + 1024;          // NWAVES+1 (+pad)
    int* erow   = ranges + (NWAVES + 2);  // E

    uintptr_t pa = (uintptr_t)(erow + E);
    pa = (pa + 255) & ~(uintptr_t)255;
    __half* eap = (__half*)pa;        // E*16 halves
    uintptr_t pb = (uintptr_t)(eap + (size_t)E * ED);
    pb = (pb + 255) & ~(uintptr_t)255;
    float* B0 = (float*)pb;
    size_t NB = (size_t)N * H;
    float* B1 = B0 + NB;
    float* B2 = B1 + NB;
    float* B3 = B2 + NB;

    const float Ninv = 1.0f / (float)N;
    dim3 rb(64, 4);
    int egrid = (E + 255) / 256;
    int ngrid = (N + 255) / 256;
    int g64 = (N + 63) / 64;
    const int SB = (N + 1023) >> 10;  // scan blocks (<=1024)

    k_prep<<<1, 64, 0, stream>>>(l1_We, l1_be, l1_Wg, l2_We, l2_be, l2_Wg, w);

    // ---- CSR build (by destination col); ea permuted to CSR order as f16 ----
    hipMemsetAsync(cnt, 0, sizeof(int) * 2 * (size_t)N, stream);
    k_count<<<egrid, 256, 0, stream>>>(cols, cnt, E);
    k_scan1<<<SB, 1024, 0, stream>>>(cnt, bs, N);
    k_scan2<<<1, 1024, 0, stream>>>(bs, SB);
    k_scan3<<<SB, 1024, 0, stream>>>(cnt, bs, rowptr, N, E);
    k_ranges<<<(NWAVES + 256) / 256, 256, 0, stream>>>(rowptr, ranges, N, E, NWAVES);
    k_scatter<<<egrid, 256, 0, stream>>>(rows, cols, ea, rowptr, cur, erow, eap, E);

    // ---- layer 1 (CIN=32) ----
    k_gather<32, false><<<WGRID, 256, 0, stream>>>(x, rowptr, ranges, erow, B0,
                                                   nullptr, nullptr, nullptr, nullptr, nullptr, 0.f, N);
    k_gemm64<32, true, false, true, false><<<g64, 256, 0, stream>>>(
        B0, 64, x, 32, l1_Wl, l1_Wr, l1_bl,
        nullptr, nullptr, nullptr, nullptr, nullptr, 0.f, rowptr, B1, N);
    k_gemm64<64, false, false, false, true><<<g64, 256, 0, stream>>>(
        B1, 64, nullptr, 0, l1_Wg, nullptr, l1_bg,
        nullptr, nullptr, nullptr, nullptr, nullptr, 0.f, rowptr, B2, N);
    k_gate<<<WGRID, 256, 0, stream>>>(rowptr, ranges, eap, wth1, wgh1, l1_be, dv1, ets1, vs1,
                                      B2, B1, stats + 0, stats + 64, N);
    k_apply<<<256, rb, 0, stream>>>(B1, B3, l1_bng, l1_bnb, stats + 0, stats + 64,
                                    stats + 128, stats + 192, Ninv, N);

    // ---- layer 2 (CIN=64); gn1 folded into readers of B3 ----
    k_gather<64, true><<<WGRID, 256, 0, stream>>>(B3, rowptr, ranges, erow, B0,
                                                  stats + 128, stats + 192, gn1_g, gn1_b, gn1_a, Ninv, N);
    k_gemm64<64, true, true, true, false><<<g64, 256, 0, stream>>>(
        B0, 64, B3, 64, l2_Wl, l2_Wr, l2_bl,
        stats + 128, stats + 192, gn1_g, gn1_b, gn1_a, Ninv, rowptr, B1, N);
    k_gemm64<64, false, false, false, true><<<g64, 256, 0, stream>>>(
        B1, 64, nullptr, 0, l2_Wg, nullptr, l2_bg,
        nullptr, nullptr, nullptr, nullptr, nullptr, 0.f, rowptr, B2, N);
    k_gate<<<WGRID, 256, 0, stream>>>(rowptr, ranges, eap, wth2, wgh2, l2_be, dv2, ets2, vs2,
                                      B2, B1, stats + 256, stats + 320, N);
    k_apply<<<256, rb, 0, stream>>>(B1, B0, l2_bng, l2_bnb, stats + 256, stats + 320,
                                    stats + 384, stats + 448, Ninv, N);

    // ---- final: gn2 fold + linear ----
    k_final<<<ngrid, 256, 0, stream>>>(B0, lin_W, lin_b, stats + 384, stats + 448,
                                       gn2_g, gn2_b, gn2_a, Ninv, (float*)d_out, N);
}

// Round 7
// 720.638 us; speedup vs baseline: 25.9935x; 1.1881x over previous
//
#include <hip/hip_runtime.h>
#include <hip/hip_fp16.h>
#include <math.h>
#include <stdint.h>

#define H 64
#define ED 16
#define CO 16
#define WGRID 2048
#define NWAVES (WGRID * 4)
static constexpr float EPSV = 1e-5f;
static constexpr float LOG2E = 1.44269504f;

typedef _Float16 h2v __attribute__((ext_vector_type(2)));

// sigmoid with pre-scaled (log2e-folded) argument: 1/(1+2^-z)
__device__ __forceinline__ float sigm2(float z) {
    return __builtin_amdgcn_rcpf(1.0f + __builtin_amdgcn_exp2f(-z));
}

__device__ __forceinline__ h2v as_h2(int x) { union { int i; h2v h; } u; u.i = x; return u.h; }

__device__ __forceinline__ int pack2(float a, float b) {
    __half2 h = __floats2half2_rn(a, b);
    return *reinterpret_cast<int*>(&h);
}

// ---------------- prep: packed-f16 gate weights (log2e-folded gate path), self-loop consts, zero stats --
// ws float layout: 0: wth1[512] 512: wgh1[512] 1024: wth2[512] 1536: wgh2[512]
//   2048: ets1[64] 2112: vs1[64] 2176: dv1[64]  2240: ets2 2304: vs2 2368: dv2   2432: stats[8][64]
__global__ void k_prep(const float* __restrict__ We1, const float* __restrict__ be1, const float* __restrict__ Wg1,
                       const float* __restrict__ We2, const float* __restrict__ be2, const float* __restrict__ Wg2,
                       float* __restrict__ ws) {
    int j = threadIdx.x;  // 0..63
    for (int l = 0; l < 2; ++l) {
        const float* We = l ? We2 : We1;
        const float* be = l ? be2 : be1;
        const float* Wg = l ? Wg2 : Wg1;
        int* wth = (int*)(ws + (l ? 1024 : 0));
        int* wgh = (int*)(ws + (l ? 1536 : 512));
        float* ets = ws + 2048 + l * 192;
        float* vs  = ws + 2112 + l * 192;
        float* dv  = ws + 2176 + l * 192;
        float wt[ED], wg[ED];
        float et = be[j];
        for (int k = 0; k < ED; ++k) { wt[k] = We[k * H + j]; et += wt[k]; }
        ets[j] = et;                                   // ea_t for self-loop (ea = ones)
        float d = 0.f;
        for (int m = 0; m < H; ++m) d += be[m] * Wg[(H + m) * H + j];
        float vsum = d;
        for (int k = 0; k < ED; ++k) {
            float acc = 0.f;
            for (int m = 0; m < H; ++m) acc += We[k * H + m] * Wg[(H + m) * H + j];
            wg[k] = acc;                               // (We @ Wg_bot)^T
            vsum += acc;
        }
        dv[j] = d * LOG2E;
        vs[j] = vsum * LOG2E;
        for (int q = 0; q < 8; ++q) {
            wth[j * 8 + q] = pack2(wt[2 * q], wt[2 * q + 1]);
            wgh[j * 8 + q] = pack2(wg[2 * q] * LOG2E, wg[2 * q + 1] * LOG2E);
        }
    }
    for (int s = 0; s < 8; ++s) ws[2432 + s * 64 + j] = 0.f;  // zero all stats
}

// ---------------- x -> f16 ----------------
__global__ void k_xh(const float* __restrict__ x, __half* __restrict__ xh, int total4) {
    int i = blockIdx.x * blockDim.x + threadIdx.x;
    if (i >= total4) return;
    float4 v = *reinterpret_cast<const float4*>(x + (size_t)i * 4);
    __half2 h0 = __floats2half2_rn(v.x, v.y), h1 = __floats2half2_rn(v.z, v.w);
    uint2 o;
    o.x = *reinterpret_cast<unsigned*>(&h0);
    o.y = *reinterpret_cast<unsigned*>(&h1);
    *reinterpret_cast<uint2*>(xh + (size_t)i * 4) = o;
}

// ---------------- CSR build ----------------
__global__ void k_count(const int* __restrict__ cols, int* __restrict__ cnt, int E) {
    int e = blockIdx.x * blockDim.x + threadIdx.x;
    if (e < E) atomicAdd(&cnt[cols[e]], 1);
}

__global__ __launch_bounds__(1024) void k_scan1(const int* __restrict__ cnt, int* __restrict__ bs, int N) {
    __shared__ int ls[1024];
    int t = threadIdx.x;
    int i = blockIdx.x * 1024 + t;
    ls[t] = (i < N) ? cnt[i] : 0;
    __syncthreads();
    for (int off = 512; off > 0; off >>= 1) {
        if (t < off) ls[t] += ls[t + off];
        __syncthreads();
    }
    if (t == 0) bs[blockIdx.x] = ls[0];
}

__global__ __launch_bounds__(1024) void k_scan2(int* __restrict__ bs, int SB) {
    __shared__ int ls[1024];
    int t = threadIdx.x;
    int v = (t < SB) ? bs[t] : 0;
    ls[t] = v;
    __syncthreads();
    for (int off = 1; off < 1024; off <<= 1) {
        int x = (t >= off) ? ls[t - off] : 0;
        __syncthreads();
        ls[t] += x;
        __syncthreads();
    }
    if (t < SB) bs[t] = ls[t] - v;  // exclusive
}

__global__ __launch_bounds__(1024) void k_scan3(const int* __restrict__ cnt, const int* __restrict__ bs,
                                                int* __restrict__ rowptr, int N, int E) {
    __shared__ int ls[1024];
    int t = threadIdx.x;
    int i = blockIdx.x * 1024 + t;
    int v = (i < N) ? cnt[i] : 0;
    ls[t] = v;
    __syncthreads();
    for (int off = 1; off < 1024; off <<= 1) {
        int x = (t >= off) ? ls[t - off] : 0;
        __syncthreads();
        ls[t] += x;
        __syncthreads();
    }
    if (i < N) rowptr[i] = bs[blockIdx.x] + ls[t] - v;  // exclusive prefix
    if (i == 0) rowptr[N] = E;
}

// ---------------- wave ranges ----------------
__global__ void k_ranges(const int* __restrict__ rowptr, int* __restrict__ ranges, int N, int E, int nw) {
    int w = blockIdx.x * blockDim.x + threadIdx.x;
    if (w > nw) return;
    if (w == nw) { ranges[nw] = N; return; }
    int t0 = (int)((long)E * w / nw);
    int lo = 0, hi = N;
    while (lo < hi) { int mid = (lo + hi) >> 1; if (rowptr[mid] < t0) lo = mid + 1; else hi = mid; }
    ranges[w] = lo;
}

// ---------------- scatter: CSR edge lists; ea permuted into CSR order as f16 ----------------
__global__ void k_scatter(const int* __restrict__ rows, const int* __restrict__ cols,
                          const float* __restrict__ ea,
                          const int* __restrict__ rowptr, int* __restrict__ cur,
                          int* __restrict__ erow, __half* __restrict__ eap, int E) {
    int e = blockIdx.x * blockDim.x + threadIdx.x;
    if (e >= E) return;
    int c = cols[e];
    int p = rowptr[c] + atomicAdd(&cur[c], 1);
    erow[p] = rows[e];
    const float4* src = reinterpret_cast<const float4*>(ea + (size_t)e * ED);
    float4 v0 = src[0], v1 = src[1], v2 = src[2], v3 = src[3];
    int hh[8];
    hh[0] = pack2(v0.x, v0.y); hh[1] = pack2(v0.z, v0.w);
    hh[2] = pack2(v1.x, v1.y); hh[3] = pack2(v1.z, v1.w);
    hh[4] = pack2(v2.x, v2.y); hh[5] = pack2(v2.z, v2.w);
    hh[6] = pack2(v3.x, v3.y); hh[7] = pack2(v3.z, v3.w);
    const int4* o = reinterpret_cast<const int4*>(hh);
    int4* dst = reinterpret_cast<int4*>(eap + (size_t)p * ED);
    dst[0] = o[0]; dst[1] = o[1];
}

// ---------------- gather (f16 input): agg[n] = T(x[n]) + sum_in T(x[row]) ----
template <int CIN, bool GN>
__global__ __launch_bounds__(256) void k_gather(const __half* __restrict__ x, const int* __restrict__ rowptr,
                         const int* __restrict__ ranges,
                         const int* __restrict__ erow, float* __restrict__ agg,
                         const float* __restrict__ s1, const float* __restrict__ s2,
                         const float* __restrict__ gng, const float* __restrict__ gnb,
                         const float* __restrict__ gna, float Ninv, int N) {
    int lane = threadIdx.x & 63;
    int w = (blockIdx.x * blockDim.x + threadIdx.x) >> 6;
    float A = 1.f, B = 0.f;
    if (GN) {
        float mu = s1[lane] * Ninv, m2 = s2[lane] * Ninv, a = gna[lane];
        float var = m2 - 2.f * a * mu * mu + a * a * mu * mu;
        A = gng[lane] * rsqrtf(var + EPSV);
        B = gnb[lane] - A * a * mu;
    }
    int n0 = ranges[w], n1 = ranges[w + 1];
    for (int n = n0; n < n1; ++n) {
        int s = rowptr[n], te = rowptr[n + 1];
        if (CIN == 64) {
            float raw = __half2float(x[(size_t)n * 64 + lane]);
            float acc = GN ? fmaxf(fmaf(A, raw, B), 0.f) : raw;
            int i = s;
            for (; i + 7 < te; i += 8) {
                int r0 = erow[i],     r1 = erow[i + 1], r2 = erow[i + 2], r3 = erow[i + 3];
                int r4 = erow[i + 4], r5 = erow[i + 5], r6 = erow[i + 6], r7 = erow[i + 7];
                float x0 = __half2float(x[(size_t)r0 * 64 + lane]);
                float x1 = __half2float(x[(size_t)r1 * 64 + lane]);
                float x2 = __half2float(x[(size_t)r2 * 64 + lane]);
                float x3 = __half2float(x[(size_t)r3 * 64 + lane]);
                float x4 = __half2float(x[(size_t)r4 * 64 + lane]);
                float x5 = __half2float(x[(size_t)r5 * 64 + lane]);
                float x6 = __half2float(x[(size_t)r6 * 64 + lane]);
                float x7 = __half2float(x[(size_t)r7 * 64 + lane]);
                if (GN) {
                    x0 = fmaxf(fmaf(A, x0, B), 0.f); x1 = fmaxf(fmaf(A, x1, B), 0.f);
                    x2 = fmaxf(fmaf(A, x2, B), 0.f); x3 = fmaxf(fmaf(A, x3, B), 0.f);
                    x4 = fmaxf(fmaf(A, x4, B), 0.f); x5 = fmaxf(fmaf(A, x5, B), 0.f);
                    x6 = fmaxf(fmaf(A, x6, B), 0.f); x7 = fmaxf(fmaf(A, x7, B), 0.f);
                }
                acc += ((x0 + x1) + (x2 + x3)) + ((x4 + x5) + (x6 + x7));
            }
            for (; i < te; ++i) {
                float xv = __half2float(x[(size_t)erow[i] * 64 + lane]);
                if (GN) xv = fmaxf(fmaf(A, xv, B), 0.f);
                acc += xv;
            }
            agg[(size_t)n * H + lane] = acc;
        } else {
            int c = lane & 31, half = lane >> 5;
            float acc = half ? 0.f : __half2float(x[(size_t)n * 32 + c]);
            int i = s + half;
            for (; i + 6 < te; i += 8) {
                int r0 = erow[i], r1 = erow[i + 2], r2 = erow[i + 4], r3 = erow[i + 6];
                float x0 = __half2float(x[(size_t)r0 * 32 + c]);
                float x1 = __half2float(x[(size_t)r1 * 32 + c]);
                float x2 = __half2float(x[(size_t)r2 * 32 + c]);
                float x3 = __half2float(x[(size_t)r3 * 32 + c]);
                acc += (x0 + x1) + (x2 + x3);
            }
            for (; i < te; i += 2) acc += __half2float(x[(size_t)erow[i] * 32 + c]);
            acc += __shfl_xor(acc, 32);
            if (half == 0) agg[(size_t)n * H + c] = acc;
        }
    }
}

// ---------------- fused GEMM: pre = (agg/deg)@Wl + T(x)@Wr + bl ; u = (pre@Wg_top + bg)*log2e ----------
#define MT4A(mq, aval) \
    acc[mq][0] = fmaf(aval, w1.x, acc[mq][0]); acc[mq][1] = fmaf(aval, w1.y, acc[mq][1]); \
    acc[mq][2] = fmaf(aval, w1.z, acc[mq][2]); acc[mq][3] = fmaf(aval, w1.w, acc[mq][3]);
#define MT4X(mq, aval) \
    acc[mq][0] = fmaf(aval, w2.x, acc[mq][0]); acc[mq][1] = fmaf(aval, w2.y, acc[mq][1]); \
    acc[mq][2] = fmaf(aval, w2.z, acc[mq][2]); acc[mq][3] = fmaf(aval, w2.w, acc[mq][3]);

template <int K, bool GN>
__global__ __launch_bounds__(256) void k_gemmfu(
        const float* __restrict__ A,               // agg, stride 64
        const __half* __restrict__ A2, int lda2,   // x-side (f16)
        const float* __restrict__ W1, const float* __restrict__ W2,
        const float* __restrict__ bias,
        const float* __restrict__ Wg, const float* __restrict__ bg,
        const float* __restrict__ s1, const float* __restrict__ s2,
        const float* __restrict__ gng, const float* __restrict__ gnb,
        const float* __restrict__ gna, float Ninv,
        const int* __restrict__ rowptr,
        float* __restrict__ pre, float* __restrict__ uout, int N) {
    __shared__ float WA[64 * 64];
    __shared__ float WB[K * 64];
    __shared__ float big[64][68];
    __shared__ float As[64], Bs[64], invd[64];
    int tid = threadIdx.x;
    for (int idx = tid; idx < K * 64; idx += 256) { WA[idx] = W1[idx]; WB[idx] = W2[idx]; }
    int nb = blockIdx.x * 64;
    if (tid < 64) {
        if (GN) {
            float mu = s1[tid] * Ninv, m2 = s2[tid] * Ninv, a = gna[tid];
            float var = m2 - 2.f * a * mu * mu + a * a * mu * mu;
            float Av = gng[tid] * rsqrtf(var + EPSV);
            As[tid] = Av; Bs[tid] = gnb[tid] - Av * a * mu;
        }
        int n = nb + tid;
        invd[tid] = (n < N) ? 1.f / (float)(rowptr[n + 1] - rowptr[n] + 1) : 0.f;
    }
    __syncthreads();
    int tm = tid >> 4, tn = tid & 15;
    int m0 = tm * 4, j0 = tn * 4;
    float acc[4][4];
#pragma unroll
    for (int jq = 0; jq < 4; ++jq) {
        float b = bias[j0 + jq];
#pragma unroll
        for (int mq = 0; mq < 4; ++mq) acc[mq][jq] = b;
    }
    int sn = tid >> 2, kq4 = (tid & 3) * 4;
    int sg = nb + sn;
    for (int k0 = 0; k0 < K; k0 += 16) {
        if (k0) __syncthreads();
        if (sg < N) {
            float4 av = *reinterpret_cast<const float4*>(A + (size_t)sg * 64 + k0 + kq4);
            float sc = invd[sn];
            av.x *= sc; av.y *= sc; av.z *= sc; av.w *= sc;
            big[kq4 + 0][sn] = av.x; big[kq4 + 1][sn] = av.y;
            big[kq4 + 2][sn] = av.z; big[kq4 + 3][sn] = av.w;
            uint2 hv = *reinterpret_cast<const uint2*>(A2 + (size_t)sg * lda2 + k0 + kq4);
            __half2 h01 = *reinterpret_cast<__half2*>(&hv.x);
            __half2 h23 = *reinterpret_cast<__half2*>(&hv.y);
            float2 f01 = __half22float2(h01), f23 = __half22float2(h23);
            float xv0 = f01.x, xv1 = f01.y, xv2 = f23.x, xv3 = f23.y;
            if (GN) {
                xv0 = fmaxf(fmaf(As[k0 + kq4 + 0], xv0, Bs[k0 + kq4 + 0]), 0.f);
                xv1 = fmaxf(fmaf(As[k0 + kq4 + 1], xv1, Bs[k0 + kq4 + 1]), 0.f);
                xv2 = fmaxf(fmaf(As[k0 + kq4 + 2], xv2, Bs[k0 + kq4 + 2]), 0.f);
                xv3 = fmaxf(fmaf(As[k0 + kq4 + 3], xv3, Bs[k0 + kq4 + 3]), 0.f);
            }
            big[16 + kq4 + 0][sn] = xv0; big[16 + kq4 + 1][sn] = xv1;
            big[16 + kq4 + 2][sn] = xv2; big[16 + kq4 + 3][sn] = xv3;
        } else {
#pragma unroll
            for (int q = 0; q < 4; ++q) { big[kq4 + q][sn] = 0.f; big[16 + kq4 + q][sn] = 0.f; }
        }
        __syncthreads();
#pragma unroll
        for (int k = 0; k < 16; ++k) {
            float4 am = *reinterpret_cast<const float4*>(&big[k][m0]);
            float4 w1 = *reinterpret_cast<const float4*>(&WA[(k0 + k) * 64 + j0]);
            MT4A(0, am.x) MT4A(1, am.y) MT4A(2, am.z) MT4A(3, am.w)
            float4 xm = *reinterpret_cast<const float4*>(&big[16 + k][m0]);
            float4 w2 = *reinterpret_cast<const float4*>(&WB[(k0 + k) * 64 + j0]);
            MT4X(0, xm.x) MT4X(1, xm.y) MT4X(2, xm.z) MT4X(3, xm.w)
        }
    }
    __syncthreads();
    // write pre + stash transposed (big[k][m] = pre[m][k])
#pragma unroll
    for (int mq = 0; mq < 4; ++mq) {
        int n = nb + m0 + mq;
        if (n < N)
            *reinterpret_cast<float4*>(pre + (size_t)n * 64 + j0) =
                make_float4(acc[mq][0], acc[mq][1], acc[mq][2], acc[mq][3]);
#pragma unroll
        for (int jq = 0; jq < 4; ++jq) big[j0 + jq][m0 + mq] = acc[mq][jq];
    }
    for (int idx = tid; idx < 4096; idx += 256) WA[idx] = Wg[idx] * LOG2E;
    __syncthreads();
    float acc2[4][4];
#pragma unroll
    for (int jq = 0; jq < 4; ++jq) {
        float b = bg[j0 + jq] * LOG2E;
#pragma unroll
        for (int mq = 0; mq < 4; ++mq) acc2[mq][jq] = b;
    }
#pragma unroll 8
    for (int k = 0; k < 64; ++k) {
        float4 pm = *reinterpret_cast<const float4*>(&big[k][m0]);
        float4 w1 = *reinterpret_cast<const float4*>(&WA[k * 64 + j0]);
        acc2[0][0] = fmaf(pm.x, w1.x, acc2[0][0]); acc2[0][1] = fmaf(pm.x, w1.y, acc2[0][1]);
        acc2[0][2] = fmaf(pm.x, w1.z, acc2[0][2]); acc2[0][3] = fmaf(pm.x, w1.w, acc2[0][3]);
        acc2[1][0] = fmaf(pm.y, w1.x, acc2[1][0]); acc2[1][1] = fmaf(pm.y, w1.y, acc2[1][1]);
        acc2[1][2] = fmaf(pm.y, w1.z, acc2[1][2]); acc2[1][3] = fmaf(pm.y, w1.w, acc2[1][3]);
        acc2[2][0] = fmaf(pm.z, w1.x, acc2[2][0]); acc2[2][1] = fmaf(pm.z, w1.y, acc2[2][1]);
        acc2[2][2] = fmaf(pm.z, w1.z, acc2[2][2]); acc2[2][3] = fmaf(pm.z, w1.w, acc2[2][3]);
        acc2[3][0] = fmaf(pm.w, w1.x, acc2[3][0]); acc2[3][1] = fmaf(pm.w, w1.y, acc2[3][1]);
        acc2[3][2] = fmaf(pm.w, w1.z, acc2[3][2]); acc2[3][3] = fmaf(pm.w, w1.w, acc2[3][3]);
    }
#pragma unroll
    for (int mq = 0; mq < 4; ++mq) {
        int n = nb + m0 + mq;
        if (n < N)
            *reinterpret_cast<float4*>(uout + (size_t)n * 64 + j0) =
                make_float4(acc2[mq][0], acc2[mq][1], acc2[mq][2], acc2[mq][3]);
    }
}

// ---------------- gate edge term: 2 dots via v_dot2_f32_f16 ----------
__device__ __forceinline__ float edge_term(const int4& a, const int4& b,
                                           const h2v* wt, const h2v* wg,
                                           float be_l, float dv_l, float u_l) {
    int ua[8] = {a.x, a.y, a.z, a.w, b.x, b.y, b.z, b.w};
    float et = be_l, v = dv_l;
#pragma unroll
    for (int q = 0; q < 8; ++q) {
        h2v e = as_h2(ua[q]);
        et = __builtin_amdgcn_fdot2(e, wt[q], et, false);
        v  = __builtin_amdgcn_fdot2(e, wg[q], v, false);
    }
    return sigm2(u_l + v) * et;
}

// ---------------- gate: LDS-staged edge stream, wave per node-range ----------------
__global__ __launch_bounds__(256) void k_gate(
        const int* __restrict__ rowptr, const int* __restrict__ ranges,
        const __half* __restrict__ eap,
        const int* __restrict__ wth, const int* __restrict__ wgh,
        const float* __restrict__ be, const float* __restrict__ dv,
        const float* __restrict__ ets, const float* __restrict__ vs,
        const float* __restrict__ u, float* __restrict__ pre,
        float* __restrict__ s1, float* __restrict__ s2, int N) {
    __shared__ __align__(16) int4 estage[4][128];   // 2KB per wave (64 edges x 32B)
    __shared__ float ls[2][4][H];
    int lane = threadIdx.x & 63;
    int wv = threadIdx.x >> 6;
    int w = (blockIdx.x << 2) | wv;
    h2v wt[8], wg[8];
#pragma unroll
    for (int q = 0; q < 8; ++q) { wt[q] = as_h2(wth[lane * 8 + q]); wg[q] = as_h2(wgh[lane * 8 + q]); }
    float be_l = be[lane], dv_l = dv[lane], ets_l = ets[lane], vs_l = vs[lane];
    int n0 = ranges[w], n1 = ranges[w + 1];
    float s = 0.f, ss = 0.f;
    if (n0 < n1) {
        int4* dst = &estage[wv][0];
        const int4* gsrc = reinterpret_cast<const int4*>(eap);
        int e0 = rowptr[n0], e1 = rowptr[n1];
        int n = n0;
        int nend = rowptr[n0 + 1];
        size_t idx = (size_t)n * H + lane;
        float u_l = u[idx];
        float pv = pre[idx];
        float acc = sigm2(u_l + vs_l) * ets_l;   // folded self-loop contribution
        {   // stage first chunk
            int bytes = min(64, e1 - e0) * 32;
            int4 p0, p1;
            if (lane * 16 < bytes) p0 = gsrc[(size_t)e0 * 2 + lane];
            if (1024 + lane * 16 < bytes) p1 = gsrc[(size_t)e0 * 2 + 64 + lane];
            if (lane * 16 < bytes) dst[lane] = p0;
            if (1024 + lane * 16 < bytes) dst[64 + lane] = p1;
        }
        for (int c = e0; c < e1; c += 64) {
            int cnt = min(64, e1 - c);
            int nbytes = (c + 64 < e1) ? min(64, e1 - c - 64) * 32 : 0;
            int4 p0, p1;
            if (lane * 16 < nbytes) p0 = gsrc[(size_t)(c + 64) * 2 + lane];
            if (1024 + lane * 16 < nbytes) p1 = gsrc[(size_t)(c + 64) * 2 + 64 + lane];
            for (int k = 0; k < cnt; ++k) {
                while (c + k == nend) {       // node boundary: finish n, start next
                    float tval = pv + acc;
                    pre[idx] = tval;
                    s += tval; ss += tval * tval;
                    ++n;
                    idx = (size_t)n * H + lane;
                    u_l = u[idx];
                    pv = pre[idx];
                    acc = sigm2(u_l + vs_l) * ets_l;
                    nend = rowptr[n + 1];
                }
                acc += edge_term(dst[k * 2], dst[k * 2 + 1], wt, wg, be_l, dv_l, u_l);
            }
            if (lane * 16 < nbytes) dst[lane] = p0;
            if (1024 + lane * 16 < nbytes) dst[64 + lane] = p1;
        }
        for (;;) {   // finish current + trailing zero-edge nodes
            float tval = pv + acc;
            pre[idx] = tval;
            s += tval; ss += tval * tval;
            ++n;
            if (n >= n1) break;
            idx = (size_t)n * H + lane;
            u_l = u[idx];
            pv = pre[idx];
            acc = sigm2(u_l + vs_l) * ets_l;
        }
    }
    ls[0][wv][lane] = s; ls[1][wv][lane] = ss;
    __syncthreads();
    if (threadIdx.x < H) {
        float a = ls[0][0][lane] + ls[0][1][lane] + ls[0][2][lane] + ls[0][3][lane];
        float b = ls[1][0][lane] + ls[1][1][lane] + ls[1][2][lane] + ls[1][3][lane];
        atomicAdd(&s1[lane], a);
        atomicAdd(&s2[lane], b);
    }
}

// ---------------- apply: h = relu(2*bn(t)) -> f16 + GraphNorm stats ----------------
__global__ void k_apply(const float* __restrict__ in, __half* __restrict__ outb,
                        const float* __restrict__ bng, const float* __restrict__ bnb,
                        const float* __restrict__ s1b, const float* __restrict__ s2b,
                        float* __restrict__ s1g, float* __restrict__ s2g, float Ninv, int N) {
    int j = threadIdx.x, ty = threadIdx.y;
    __shared__ float As[H], Bs[H];
    if (ty == 0) {
        float mu = s1b[j] * Ninv, var = s2b[j] * Ninv - mu * mu;
        float r = rsqrtf(var + EPSV);
        float A = 2.f * bng[j] * r;
        As[j] = A; Bs[j] = 2.f * (bnb[j] - bng[j] * r * mu);
    }
    __syncthreads();
    float A = As[j], B = Bs[j];
    float s = 0.f, ss = 0.f;
    for (int n = blockIdx.x * 4 + ty; n < N; n += gridDim.x * 4) {
        size_t idx = (size_t)n * H + j;
        float v = fmaxf(fmaf(A, in[idx], B), 0.f);
        outb[idx] = __float2half(v);
        s += v; ss += v * v;
    }
    __shared__ float ls[2][4][H];
    ls[0][ty][j] = s; ls[1][ty][j] = ss;
    __syncthreads();
    if (ty == 0) {
        float a = ls[0][0][j] + ls[0][1][j] + ls[0][2][j] + ls[0][3][j];
        float b = ls[1][0][j] + ls[1][1][j] + ls[1][2][j] + ls[1][3][j];
        atomicAdd(&s1g[j], a);
        atomicAdd(&s2g[j], b);
    }
}

// ---------------- final: out = relu(gn2(h)) @ lin_W + lin_b ----------------
__global__ __launch_bounds__(256) void k_final(const __half* __restrict__ hraw, const float* __restrict__ W,
                        const float* __restrict__ bias,
                        const float* __restrict__ s1, const float* __restrict__ s2,
                        const float* __restrict__ gng, const float* __restrict__ gnb,
                        const float* __restrict__ gna, float Ninv,
                        float* __restrict__ outp, int N) {
    __shared__ float As[H], Bs[H];
    if (threadIdx.x < H) {
        int j = threadIdx.x;
        float mu = s1[j] * Ninv, m2 = s2[j] * Ninv, a = gna[j];
        float var = m2 - 2.f * a * mu * mu + a * a * mu * mu;
        float A = gng[j] * rsqrtf(var + EPSV);
        As[j] = A; Bs[j] = gnb[j] - A * a * mu;
    }
    __syncthreads();
    int n = blockIdx.x * blockDim.x + threadIdx.x;
    if (n >= N) return;
    float o[CO];
#pragma unroll
    for (int t = 0; t < CO; ++t) o[t] = bias[t];
    const __half* hr = hraw + (size_t)n * H;
    for (int m4 = 0; m4 < H / 4; ++m4) {
        uint2 hv = *reinterpret_cast<const uint2*>(hr + m4 * 4);
        __half2 h01 = *reinterpret_cast<__half2*>(&hv.x);
        __half2 h23 = *reinterpret_cast<__half2*>(&hv.y);
        float2 f01 = __half22float2(h01), f23 = __half22float2(h23);
        float hx = fmaxf(fmaf(As[m4*4+0], f01.x, Bs[m4*4+0]), 0.f);
        float hy = fmaxf(fmaf(As[m4*4+1], f01.y, Bs[m4*4+1]), 0.f);
        float hz = fmaxf(fmaf(As[m4*4+2], f23.x, Bs[m4*4+2]), 0.f);
        float hw = fmaxf(fmaf(As[m4*4+3], f23.y, Bs[m4*4+3]), 0.f);
#pragma unroll
        for (int t = 0; t < CO; ++t) {
            o[t] += hx * W[(m4*4+0) * CO + t];
            o[t] += hy * W[(m4*4+1) * CO + t];
            o[t] += hz * W[(m4*4+2) * CO + t];
            o[t] += hw * W[(m4*4+3) * CO + t];
        }
    }
    float* orow = outp + (size_t)n * CO;
#pragma unroll
    for (int t4 = 0; t4 < CO / 4; ++t4)
        reinterpret_cast<float4*>(orow)[t4] = make_float4(o[t4*4+0], o[t4*4+1], o[t4*4+2], o[t4*4+3]);
}

extern "C" void kernel_launch(void* const* d_in, const int* in_sizes, int n_in,
                              void* d_out, int out_size, void* d_ws, size_t ws_size,
                              hipStream_t stream) {
    const float* x     = (const float*)d_in[0];
    const int*   ei    = (const int*)d_in[1];
    const float* ea    = (const float*)d_in[2];
    const float* l1_Wl = (const float*)d_in[3];  const float* l1_bl = (const float*)d_in[4];
    const float* l1_Wr = (const float*)d_in[5];  const float* l1_We = (const float*)d_in[6];
    const float* l1_be = (const float*)d_in[7];  const float* l1_Wg = (const float*)d_in[8];
    const float* l1_bg = (const float*)d_in[9];  const float* l1_bng= (const float*)d_in[10];
    const float* l1_bnb= (const float*)d_in[11];
    const float* l2_Wl = (const float*)d_in[12]; const float* l2_bl = (const float*)d_in[13];
    const float* l2_Wr = (const float*)d_in[14]; const float* l2_We = (const float*)d_in[15];
    const float* l2_be = (const float*)d_in[16]; const float* l2_Wg = (const float*)d_in[17];
    const float* l2_bg = (const float*)d_in[18]; const float* l2_bng= (const float*)d_in[19];
    const float* l2_bnb= (const float*)d_in[20];
    const float* gn1_g = (const float*)d_in[21]; const float* gn1_b = (const float*)d_in[22];
    const float* gn1_a = (const float*)d_in[23];
    const float* gn2_g = (const float*)d_in[24]; const float* gn2_b = (const float*)d_in[25];
    const float* gn2_a = (const float*)d_in[26];
    const float* lin_W = (const float*)d_in[27]; const float* lin_b = (const float*)d_in[28];

    const int N = in_sizes[0] / 32;
    const int E = in_sizes[1] / 2;
    const int* rows = ei;
    const int* cols = ei + E;

    float* w    = (float*)d_ws;
    int* wth1   = (int*)w;
    int* wgh1   = (int*)(w + 512);
    int* wth2   = (int*)(w + 1024);
    int* wgh2   = (int*)(w + 1536);
    float* ets1 = w + 2048; float* vs1 = w + 2112; float* dv1 = w + 2176;
    float* ets2 = w + 2240; float* vs2 = w + 2304; float* dv2 = w + 2368;
    float* stats= w + 2432;

    int* ip     = (int*)(w + 8192);
    int* rowptr = ip;                 // N+1
    int* cnt    = ip + (N + 1);       // N
    int* cur    = cnt + N;            // N (contiguous with cnt for one memset)
    int* bs     = cur + N;            // scan block sums
    int* ranges = bs + 1024;          // NWAVES+1
    int* erow   = ranges + (NWAVES + 2);  // E

    uintptr_t pa = (uintptr_t)(erow + E);
    pa = (pa + 255) & ~(uintptr_t)255;
    __half* eap = (__half*)pa;        // E*16 halves
    uintptr_t pb = (uintptr_t)(eap + (size_t)E * ED);
    pb = (pb + 255) & ~(uintptr_t)255;
    float* B0 = (float*)pb;
    size_t NB = (size_t)N * H;
    float* B1 = B0 + NB;
    float* B2 = B1 + NB;
    __half* xh  = (__half*)(B2 + NB);        // N*32 halves
    __half* B3h = xh + (size_t)N * 32;       // N*64 halves
    __half* B0h = (__half*)B0;               // layer-2 h reuses B0 space

    const float Ninv = 1.0f / (float)N;
    dim3 rb(64, 4);
    int egrid = (E + 255) / 256;
    int ngrid = (N + 255) / 256;
    int g64 = (N + 63) / 64;
    const int SB = (N + 1023) >> 10;

    k_prep<<<1, 64, 0, stream>>>(l1_We, l1_be, l1_Wg, l2_We, l2_be, l2_Wg, w);
    k_xh<<<(N * 8 + 255) / 256, 256, 0, stream>>>(x, xh, N * 8);

    // ---- CSR build ----
    hipMemsetAsync(cnt, 0, sizeof(int) * 2 * (size_t)N, stream);
    k_count<<<egrid, 256, 0, stream>>>(cols, cnt, E);
    k_scan1<<<SB, 1024, 0, stream>>>(cnt, bs, N);
    k_scan2<<<1, 1024, 0, stream>>>(bs, SB);
    k_scan3<<<SB, 1024, 0, stream>>>(cnt, bs, rowptr, N, E);
    k_ranges<<<(NWAVES + 256) / 256, 256, 0, stream>>>(rowptr, ranges, N, E, NWAVES);
    k_scatter<<<egrid, 256, 0, stream>>>(rows, cols, ea, rowptr, cur, erow, eap, E);

    // ---- layer 1 ----
    k_gather<32, false><<<WGRID, 256, 0, stream>>>(xh, rowptr, ranges, erow, B0,
                                                   nullptr, nullptr, nullptr, nullptr, nullptr, 0.f, N);
    k_gemmfu<32, false><<<g64, 256, 0, stream>>>(B0, xh, 32, l1_Wl, l1_Wr, l1_bl, l1_Wg, l1_bg,
                                                 nullptr, nullptr, nullptr, nullptr, nullptr, 0.f,
                                                 rowptr, B1, B2, N);
    k_gate<<<WGRID, 256, 0, stream>>>(rowptr, ranges, eap, wth1, wgh1, l1_be, dv1, ets1, vs1,
                                      B2, B1, stats + 0, stats + 64, N);
    k_apply<<<256, rb, 0, stream>>>(B1, B3h, l1_bng, l1_bnb, stats + 0, stats + 64,
                                    stats + 128, stats + 192, Ninv, N);

    // ---- layer 2 (gn1 folded into readers of B3h) ----
    k_gather<64, true><<<WGRID, 256, 0, stream>>>(B3h, rowptr, ranges, erow, B0,
                                                  stats + 128, stats + 192, gn1_g, gn1_b, gn1_a, Ninv, N);
    k_gemmfu<64, true><<<g64, 256, 0, stream>>>(B0, B3h, 64, l2_Wl, l2_Wr, l2_bl, l2_Wg, l2_bg,
                                                stats + 128, stats + 192, gn1_g, gn1_b, gn1_a, Ninv,
                                                rowptr, B1, B2, N);
    k_gate<<<WGRID, 256, 0, stream>>>(rowptr, ranges, eap, wth2, wgh2, l2_be, dv2, ets2, vs2,
                                      B2, B1, stats + 256, stats + 320, N);
    k_apply<<<256, rb, 0, stream>>>(B1, B0h, l2_bng, l2_bnb, stats + 256, stats + 320,
                                    stats + 384, stats + 448, Ninv, N);

    // ---- final ----
    k_final<<<ngrid, 256, 0, stream>>>(B0h, lin_W, lin_b, stats + 384, stats + 448,
                                       gn2_g, gn2_b, gn2_a, Ninv, (float*)d_out, N);
}